// Round 13
// baseline (232.535 us; speedup 1.0000x reference)
//
#include <hip/hip_runtime.h>

#define KDIM 256
#define NB 16384
#define NR 8192
#define CHUNK 1088            // 1024B data + 64B pad per 8-row chunk

typedef unsigned short ushort_t;
typedef unsigned long long u64;
typedef __attribute__((ext_vector_type(8))) short short8;
typedef __attribute__((ext_vector_type(4))) float f32x4;

// ---------------------------------------------------------------- helpers ---
__device__ __forceinline__ ushort_t f2bf(float f) {          // RNE f32->bf16
    unsigned u = __float_as_uint(f);
    unsigned r = (u + 0x7fffu + ((u >> 16) & 1u)) >> 16;
    return (ushort_t)r;
}
__device__ __forceinline__ void gload16(const void* g, void* l) {
    __builtin_amdgcn_global_load_lds(
        (const __attribute__((address_space(1))) void*)g,
        (__attribute__((address_space(3))) void*)l, 16, 0, 0);
}
// 16-lane all-reduce max on the VALU pipe: v_max through DPP row rotations
__device__ __forceinline__ unsigned rowmax16(unsigned m) {
    unsigned t;
    t = (unsigned)__builtin_amdgcn_update_dpp(0, (int)m, 0x121, 0xf, 0xf, true);
    m = t > m ? t : m;
    t = (unsigned)__builtin_amdgcn_update_dpp(0, (int)m, 0x122, 0xf, 0xf, true);
    m = t > m ? t : m;
    t = (unsigned)__builtin_amdgcn_update_dpp(0, (int)m, 0x124, 0xf, 0xf, true);
    m = t > m ? t : m;
    t = (unsigned)__builtin_amdgcn_update_dpp(0, (int)m, 0x128, 0xf, 0xf, true);
    m = t > m ? t : m;
    return m;
}
// branchless insert into sorted top-3 (v desc, idx asc on ties)
__device__ __forceinline__ void ins3(float v, int idx,
                                     float& v0, int& i0, float& v1, int& i1,
                                     float& v2, int& i2) {
    bool b0 = (v > v0) | ((v == v0) & (idx < i0));
    bool b1 = (v > v1) | ((v == v1) & (idx < i1));
    bool b2 = (v > v2) | ((v == v2) & (idx < i2));
    float nv2 = b1 ? v1 : (b2 ? v : v2);
    int   ni2 = b1 ? i1 : (b2 ? idx : i2);
    float nv1 = b0 ? v0 : (b1 ? v : v1);
    int   ni1 = b0 ? i0 : (b1 ? idx : i1);
    float nv0 = b0 ? v : v0;
    int   ni0 = b0 ? idx : i0;
    v0 = nv0; i0 = ni0; v1 = nv1; i1 = ni1; v2 = nv2; i2 = ni2;
}
__device__ __forceinline__ void ins3f(float v, int idx, float* tv, int* ti) {
    ins3(v, idx, tv[0], ti[0], tv[1], ti[1], tv[2], ti[2]);
}

// ----------------- split: normalize + single bf16 (h) conversion ------------
__global__ __launch_bounds__(256) void split_h_kernel(
    const float* __restrict__ base, const float* __restrict__ real,
    ushort_t* __restrict__ Ah, ushort_t* __restrict__ Bh,
    float* __restrict__ inv) {
    int rid  = blockIdx.x * 4 + (threadIdx.x >> 6);
    int lane = threadIdx.x & 63;
    bool isA = rid < NB;
    int  row = isA ? rid : rid - NB;
    const float* src = isA ? base + (size_t)row * KDIM : real + (size_t)row * KDIM;
    float4 v = *(const float4*)(src + lane * 4);
    float ss = v.x * v.x + v.y * v.y + v.z * v.z + v.w * v.w;
    #pragma unroll
    for (int off = 32; off > 0; off >>= 1) ss += __shfl_xor(ss, off);
    float invn = 1.0f / fmaxf(sqrtf(ss), 1e-12f);

    ushort4 h4 = make_ushort4(f2bf(v.x * invn), f2bf(v.y * invn),
                              f2bf(v.z * invn), f2bf(v.w * invn));
    *(ushort4*)((isA ? Ah : Bh) + (size_t)row * KDIM + lane * 4) = h4;
    if (lane == 0) inv[rid] = invn;
}

// --------------------- bf16 MFMA GEMM (K=256) + per-block top-4 keys --------
// block 256 thr = 4 waves (2x2), tile 128x128, BK=64, 4 K-iterations.
// Single-buffered padded-chunk LDS (34816B -> 4 blocks/CU; TLP hides the
// staging wait — R9 showed prefetch is worth only ~9us here). Loop shape is
// R7's proven {sync; stage; sync; compute}. Chunk pad (R10-proven) keeps
// frag reads conflict-free; staging stays linear per chunk.
__global__ __launch_bounds__(256) void mfma_topk_kernel(
    const ushort_t* __restrict__ Ah, const ushort_t* __restrict__ Bh,
    unsigned* __restrict__ Pk) {
    __shared__ char sAb[16 * CHUNK];
    __shared__ char sBb[16 * CHUNK];

    const int tid  = threadIdx.x;
    const int lane = tid & 63;
    const int w    = tid >> 6;
    const int wr   = w >> 1, wc = w & 1;
    const int c    = lane & 15;       // frag col/row-in-16
    const int kg   = lane >> 4;       // frag k-group (0..3)
    const int lr8  = lane >> 3;       // staging: row within 8-row chunk
    const int ud   = lane & 7;        // staging: 16B slot within row (linear)

    // ---- bijective XCD supertile remap: 8192 blocks = 8 XCD x 16 st x 8x8 --
    int lin = blockIdx.y * 64 + blockIdx.x;     // gridDim = (64, 128)
    int xcd = lin & 7;
    int pos = lin >> 3;                          // 0..1023
    int gg  = xcd * 1024 + pos;                  // chunked per-XCD range
    int st  = gg >> 6, in8 = gg & 63;            // supertile id, pos within
    int my  = ((st >> 3) << 3) + (in8 >> 3);     // 0..127 row tile
    int nx  = ((st & 7) << 3) + (in8 & 7);       // 0..63  col tile
    const int m0 = my * 128;
    const int n0 = nx * 128;

    f32x4 acc[4][4];
    #pragma unroll
    for (int i = 0; i < 4; ++i)
        #pragma unroll
        for (int j = 0; j < 4; ++j) acc[i][j] = (f32x4){0.f, 0.f, 0.f, 0.f};

    #pragma unroll 1
    for (int kc = 0; kc < KDIM; kc += 64) {
        __syncthreads();   // LDS free (prev compute done)
        #pragma unroll
        for (int q = 0; q < 4; ++q) {
            int cq = w * 4 + q;                   // chunk id 0..15
            gload16(Ah + (size_t)(m0 + cq * 8 + lr8) * KDIM + kc + ud * 8,
                    sAb + cq * CHUNK);
            gload16(Bh + (size_t)(n0 + cq * 8 + lr8) * KDIM + kc + ud * 8,
                    sBb + cq * CHUNK);
        }
        __syncthreads();   // staging complete (vmcnt drain)
        #pragma unroll
        for (int kk = 0; kk < 2; ++kk) {
            short8 a[4], b[4];
            int u = kk * 4 + kg;
            #pragma unroll
            for (int i = 0; i < 4; ++i) {
                int ra = wr * 64 + i * 16 + c;
                a[i] = *(const short8*)(sAb + (ra >> 3) * CHUNK +
                                        (ra & 7) * 128 + u * 16);
                int rb = wc * 64 + i * 16 + c;
                b[i] = *(const short8*)(sBb + (rb >> 3) * CHUNK +
                                        (rb & 7) * 128 + u * 16);
            }
            #pragma unroll
            for (int i = 0; i < 4; ++i)
                #pragma unroll
                for (int j = 0; j < 4; ++j)
                    acc[i][j] = __builtin_amdgcn_mfma_f32_16x16x32_bf16(
                        a[i], b[j], acc[i][j], 0, 0, 0);
        }
    }

    // ---- per-row top-4 keys over this block's 128 cols ----
    __syncthreads();                       // done reading tiles; reuse LDS
    unsigned* mk = (unsigned*)sAb;         // [128][2][4] keys (LDS reuse)
    #pragma unroll
    for (int i = 0; i < 4; ++i) {
        #pragma unroll
        for (int r = 0; r < 4; ++r) {
            unsigned k0 = ((__float_as_uint(acc[i][0][r] + 2.0f) - 0x3F800000u) << 7)
                          | (unsigned)(wc * 64 + 0 * 16 + c);
            unsigned k1 = ((__float_as_uint(acc[i][1][r] + 2.0f) - 0x3F800000u) << 7)
                          | (unsigned)(wc * 64 + 1 * 16 + c);
            unsigned k2 = ((__float_as_uint(acc[i][2][r] + 2.0f) - 0x3F800000u) << 7)
                          | (unsigned)(wc * 64 + 2 * 16 + c);
            unsigned k3 = ((__float_as_uint(acc[i][3][r] + 2.0f) - 0x3F800000u) << 7)
                          | (unsigned)(wc * 64 + 3 * 16 + c);
            unsigned top[4];
            #pragma unroll
            for (int p = 0; p < 4; ++p) {
                unsigned m01 = k0 > k1 ? k0 : k1;
                unsigned m23 = k2 > k3 ? k2 : k3;
                unsigned m   = m01 > m23 ? m01 : m23;
                m = rowmax16(m);           // VALU DPP, no DS ops
                top[p] = m;
                k0 = (k0 == m) ? 0u : k0;
                k1 = (k1 == m) ? 0u : k1;
                k2 = (k2 == m) ? 0u : k2;
                k3 = (k3 == m) ? 0u : k3;
            }
            if (c == 0) {
                int row = wr * 64 + i * 16 + kg * 4 + r;
                *(uint4*)&mk[(row * 2 + wc) * 4] =
                    make_uint4(top[0], top[1], top[2], top[3]);
            }
        }
    }
    __syncthreads();
    if (tid < 128) {
        unsigned e[8];
        *(uint4*)&e[0] = *(const uint4*)&mk[tid * 8];
        *(uint4*)&e[4] = *(const uint4*)&mk[tid * 8 + 4];
        unsigned top[4];
        #pragma unroll
        for (int p = 0; p < 4; ++p) {
            unsigned m = e[0];
            #pragma unroll
            for (int q = 1; q < 8; ++q) m = e[q] > m ? e[q] : m;
            top[p] = m;
            #pragma unroll
            for (int q = 0; q < 8; ++q) e[q] = (e[q] == m) ? 0u : e[q];
        }
        size_t o = (size_t)(m0 + tid) * 256 + nx * 4;   // [row][64 blocks][4]
        *(uint4*)&Pk[o] = make_uint4(top[0], top[1], top[2], top[3]);
    }
}

// ---- stage-2: u64-key butterfly -> global top-8, exact f32 rerank of 8 -----
// ekey = val24 << 13 | (8191 - idx): monotone in value, idx-asc on ties.
// Rerank reproduces round-1's exact arithmetic (sequential fmaf chain).
__global__ __launch_bounds__(256) void merge8_kernel(
    const unsigned* __restrict__ Pk,
    const float* __restrict__ base, const float* __restrict__ real,
    const float* __restrict__ inv, int* __restrict__ out) {
    int row  = blockIdx.x * 4 + (threadIdx.x >> 6);
    int lane = threadIdx.x & 63;
    uint4 kv = *(const uint4*)(Pk + (size_t)row * 256 + lane * 4);

    // expand to u64 keys with full global index (this lane's block nx == lane)
    u64 k[4];
    {
        unsigned kk[4] = {kv.x, kv.y, kv.z, kv.w};
        #pragma unroll
        for (int e = 0; e < 4; ++e) {
            int idx = lane * 128 + (int)(kk[e] & 127u);
            k[e] = ((u64)(kk[e] >> 7) << 13) | (unsigned)(8191 - idx);
        }
    }

    int cnd[8];
    #pragma unroll
    for (int p = 0; p < 8; ++p) {
        u64 m01 = k[0] > k[1] ? k[0] : k[1];
        u64 m23 = k[2] > k[3] ? k[2] : k[3];
        u64 m   = m01 > m23 ? m01 : m23;
        #pragma unroll
        for (int mask = 1; mask <= 32; mask <<= 1) {
            u64 om = __shfl_xor(m, mask);
            m = om > m ? om : m;
        }
        cnd[p] = 8191 - (int)(m & 8191u);
        #pragma unroll
        for (int e = 0; e < 4; ++e) k[e] = (k[e] == m) ? 0ull : k[e];
    }

    // exact f32 re-rank of the 8 candidates (one per lane 0..7)
    int cand = cnd[0];
    #pragma unroll
    for (int l = 1; l < 8; ++l) cand = (lane == l) ? cnd[l] : cand;
    float s = 0.0f;
    if (lane < 8) {
        const float* a = base + (size_t)row  * KDIM;
        const float* b = real + (size_t)cand * KDIM;
        float ia = inv[row], ib = inv[NB + cand];
        #pragma unroll 4
        for (int kq = 0; kq < KDIM; kq += 4) {
            float4 av = *(const float4*)(a + kq);
            float4 bv = *(const float4*)(b + kq);
            s = fmaf(av.x * ia, bv.x * ib, s);
            s = fmaf(av.y * ia, bv.y * ib, s);
            s = fmaf(av.z * ia, bv.z * ib, s);
            s = fmaf(av.w * ia, bv.w * ib, s);
        }
    }
    float fv0 = -3.0e38f, fv1 = -3.0e38f, fv2 = -3.0e38f;
    int   fi0 = 0x7fffffff, fi1 = 0x7fffffff, fi2 = 0x7fffffff;
    #pragma unroll
    for (int l = 0; l < 8; ++l) {
        float sv = __shfl(s, l);
        int   si = __shfl(cand, l);
        ins3(sv, si, fv0, fi0, fv1, fi1, fv2, fi2);
    }
    if (lane == 0) {
        out[row * 3 + 0] = fi0;
        out[row * 3 + 1] = fi1;
        out[row * 3 + 2] = fi2;
    }
}

// ======================= fallback (round-1 f32 path) ========================
__global__ __launch_bounds__(256) void norm_kernel(const float* __restrict__ base,
                                                   const float* __restrict__ real,
                                                   float* __restrict__ inv) {
    int rid  = blockIdx.x * 4 + (threadIdx.x >> 6);
    int lane = threadIdx.x & 63;
    if (rid >= NB + NR) return;
    const float* src = (rid < NB) ? (base + (size_t)rid * KDIM)
                                  : (real + (size_t)(rid - NB) * KDIM);
    float4 v = *(const float4*)(src + lane * 4);
    float ss = v.x * v.x + v.y * v.y + v.z * v.z + v.w * v.w;
    #pragma unroll
    for (int off = 32; off > 0; off >>= 1) ss += __shfl_xor(ss, off);
    if (lane == 0) inv[rid] = 1.0f / fmaxf(sqrtf(ss), 1e-12f);
}

#define DOT(i, j, av, bv)                                                      \
    acc[i][j] = fmaf(av.x, bv.x, acc[i][j]);                                   \
    acc[i][j] = fmaf(av.y, bv.y, acc[i][j]);                                   \
    acc[i][j] = fmaf(av.z, bv.z, acc[i][j]);                                   \
    acc[i][j] = fmaf(av.w, bv.w, acc[i][j]);

__global__ __launch_bounds__(256) void simtopk_kernel(
    const float* __restrict__ A, const float* __restrict__ B,
    const float* __restrict__ invA, const float* __restrict__ invB,
    int* __restrict__ out) {
    __shared__ float sA[64 * 68];
    __shared__ float sB[64 * 68];
    const int tid = threadIdx.x;
    const int tx  = tid & 15;
    const int ty4 = (tid >> 4) << 2;
    const int m0  = blockIdx.x * 64;
    float t3v[4][3];
    int   t3i[4][3];
    #pragma unroll
    for (int i = 0; i < 4; ++i)
        #pragma unroll
        for (int s = 0; s < 3; ++s) { t3v[i][s] = -3.0e38f; t3i[i][s] = 0x7fffffff; }
    for (int nn0 = 0; nn0 < NR; nn0 += 64) {
        float acc[4][4] = {{0.f}};
        for (int kc = 0; kc < KDIM; kc += 64) {
            __syncthreads();
            #pragma unroll
            for (int p = 0; p < 4; ++p) {
                int f = tid + (p << 8), row = f >> 4, c4 = (f & 15) << 2;
                float4 va = *(const float4*)(A + (size_t)(m0 + row) * KDIM + kc + c4);
                float  sa = invA[m0 + row];
                va.x *= sa; va.y *= sa; va.z *= sa; va.w *= sa;
                *(float4*)&sA[row * 68 + c4] = va;
                float4 vb = *(const float4*)(B + (size_t)(nn0 + row) * KDIM + kc + c4);
                float  sb = invB[nn0 + row];
                vb.x *= sb; vb.y *= sb; vb.z *= sb; vb.w *= sb;
                *(float4*)&sB[row * 68 + c4] = vb;
            }
            __syncthreads();
            #pragma unroll
            for (int k = 0; k < 64; k += 4) {
                float4 a0 = *(const float4*)&sA[(ty4 + 0) * 68 + k];
                float4 a1 = *(const float4*)&sA[(ty4 + 1) * 68 + k];
                float4 a2 = *(const float4*)&sA[(ty4 + 2) * 68 + k];
                float4 a3 = *(const float4*)&sA[(ty4 + 3) * 68 + k];
                float4 b0 = *(const float4*)&sB[(tx +  0) * 68 + k];
                float4 b1 = *(const float4*)&sB[(tx + 16) * 68 + k];
                float4 b2 = *(const float4*)&sB[(tx + 32) * 68 + k];
                float4 b3 = *(const float4*)&sB[(tx + 48) * 68 + k];
                DOT(0,0,a0,b0) DOT(0,1,a0,b1) DOT(0,2,a0,b2) DOT(0,3,a0,b3)
                DOT(1,0,a1,b0) DOT(1,1,a1,b1) DOT(1,2,a1,b2) DOT(1,3,a1,b3)
                DOT(2,0,a2,b0) DOT(2,1,a2,b1) DOT(2,2,a2,b2) DOT(2,3,a2,b3)
                DOT(3,0,a3,b0) DOT(3,1,a3,b1) DOT(3,2,a3,b2) DOT(3,3,a3,b3)
            }
        }
        #pragma unroll
        for (int i = 0; i < 4; ++i)
            #pragma unroll
            for (int j = 0; j < 4; ++j)
                ins3f(acc[i][j], nn0 + tx + 16 * j, t3v[i], t3i[i]);
    }
    __syncthreads();
    float* mv = sA;
    int*   mi = (int*)sB;
    #pragma unroll
    for (int i = 0; i < 4; ++i)
        #pragma unroll
        for (int s = 0; s < 3; ++s) {
            mv[(ty4 + i) * 48 + tx * 3 + s] = t3v[i][s];
            mi[(ty4 + i) * 48 + tx * 3 + s] = t3i[i][s];
        }
    __syncthreads();
    if (tid < 64) {
        float v0 = -3.0e38f, v1 = -3.0e38f, v2 = -3.0e38f;
        int   i0 = 0x7fffffff, i1 = 0x7fffffff, i2 = 0x7fffffff;
        for (int e = 0; e < 48; ++e)
            ins3(mv[tid * 48 + e], mi[tid * 48 + e], v0, i0, v1, i1, v2, i2);
        out[(m0 + tid) * 3 + 0] = i0;
        out[(m0 + tid) * 3 + 1] = i1;
        out[(m0 + tid) * 3 + 2] = i2;
    }
}

// ============================================================== launcher ====
extern "C" void kernel_launch(void* const* d_in, const int* in_sizes, int n_in,
                              void* d_out, int out_size, void* d_ws, size_t ws_size,
                              hipStream_t stream) {
    const float* base = (const float*)d_in[0];
    const float* real = (const float*)d_in[1];
    int* out = (int*)d_out;

    const size_t szAh  = (size_t)NB * KDIM * 2;      // 8.4 MB
    const size_t szBh  = (size_t)NR * KDIM * 2;      // 4.2 MB
    const size_t szPk  = (size_t)NB * 256 * 4;       // 16.8 MB
    const size_t szInv = (size_t)(NB + NR) * 4;      // 0.1 MB
    const size_t need  = szAh + szBh + szPk + szInv;

    if (ws_size >= need) {
        char* p = (char*)d_ws;
        ushort_t* Ah  = (ushort_t*)(p);
        ushort_t* Bh  = (ushort_t*)(p + szAh);
        unsigned* Pk  = (unsigned*)(p + szAh + szBh);
        float*    inv = (float*)   (p + szAh + szBh + szPk);

        hipLaunchKernelGGL(split_h_kernel, dim3((NB + NR) / 4), dim3(256), 0, stream,
                           base, real, Ah, Bh, inv);
        hipLaunchKernelGGL(mfma_topk_kernel, dim3(NR / 128, NB / 128), dim3(256), 0,
                           stream, Ah, Bh, Pk);
        hipLaunchKernelGGL(merge8_kernel, dim3(NB / 4), dim3(256), 0, stream,
                           Pk, base, real, inv, out);
    } else {
        float* inv = (float*)d_ws;
        hipLaunchKernelGGL(norm_kernel, dim3((NB + NR) / 4), dim3(256), 0, stream,
                           base, real, inv);
        hipLaunchKernelGGL(simtopk_kernel, dim3(NB / 64), dim3(256), 0, stream,
                           base, real, inv, inv + NB, out);
    }
}

// Round 14
// 209.366 us; speedup vs baseline: 1.1107x; 1.1107x over previous
//
#include <hip/hip_runtime.h>

#define KDIM 256
#define NB 16384
#define NR 8192
#define CHUNK 1088            // 1024B data + 64B pad per 8-row chunk

typedef unsigned short ushort_t;
typedef __attribute__((ext_vector_type(8))) short short8;
typedef __attribute__((ext_vector_type(4))) float f32x4;

// ---------------------------------------------------------------- helpers ---
__device__ __forceinline__ ushort_t f2bf(float f) {          // RNE f32->bf16
    unsigned u = __float_as_uint(f);
    unsigned r = (u + 0x7fffu + ((u >> 16) & 1u)) >> 16;
    return (ushort_t)r;
}
__device__ __forceinline__ void gload16(const void* g, void* l) {
    __builtin_amdgcn_global_load_lds(
        (const __attribute__((address_space(1))) void*)g,
        (__attribute__((address_space(3))) void*)l, 16, 0, 0);
}
// 16-lane all-reduce max on the VALU pipe: v_max through DPP row rotations
__device__ __forceinline__ unsigned rowmax16(unsigned m) {
    unsigned t;
    t = (unsigned)__builtin_amdgcn_update_dpp(0, (int)m, 0x121, 0xf, 0xf, true);
    m = t > m ? t : m;
    t = (unsigned)__builtin_amdgcn_update_dpp(0, (int)m, 0x122, 0xf, 0xf, true);
    m = t > m ? t : m;
    t = (unsigned)__builtin_amdgcn_update_dpp(0, (int)m, 0x124, 0xf, 0xf, true);
    m = t > m ? t : m;
    t = (unsigned)__builtin_amdgcn_update_dpp(0, (int)m, 0x128, 0xf, 0xf, true);
    m = t > m ? t : m;
    return m;
}
// branchless insert into sorted top-3 (v desc, idx asc on ties)
__device__ __forceinline__ void ins3(float v, int idx,
                                     float& v0, int& i0, float& v1, int& i1,
                                     float& v2, int& i2) {
    bool b0 = (v > v0) | ((v == v0) & (idx < i0));
    bool b1 = (v > v1) | ((v == v1) & (idx < i1));
    bool b2 = (v > v2) | ((v == v2) & (idx < i2));
    float nv2 = b1 ? v1 : (b2 ? v : v2);
    int   ni2 = b1 ? i1 : (b2 ? idx : i2);
    float nv1 = b0 ? v0 : (b1 ? v : v1);
    int   ni1 = b0 ? i0 : (b1 ? idx : i1);
    float nv0 = b0 ? v : v0;
    int   ni0 = b0 ? idx : i0;
    v0 = nv0; i0 = ni0; v1 = nv1; i1 = ni1; v2 = nv2; i2 = ni2;
}
__device__ __forceinline__ void ins3f(float v, int idx, float* tv, int* ti) {
    ins3(v, idx, tv[0], ti[0], tv[1], ti[1], tv[2], ti[2]);
}

// GEMM tile helpers (R10-proven addressing)
__device__ __forceinline__ void issue_tile(
    const ushort_t* __restrict__ Ah, const ushort_t* __restrict__ Bh,
    int m0, int n0, int kc, int w, int lr8, int ud, char* dA, char* dB) {
    #pragma unroll
    for (int q = 0; q < 4; ++q) {
        int cq = w * 4 + q;
        gload16(Ah + (size_t)(m0 + cq * 8 + lr8) * KDIM + kc + ud * 8,
                dA + cq * CHUNK);
        gload16(Bh + (size_t)(n0 + cq * 8 + lr8) * KDIM + kc + ud * 8,
                dB + cq * CHUNK);
    }
}
__device__ __forceinline__ void compute_tile(
    const char* rA, const char* rB, int wr, int wc, int c, int kg,
    f32x4 (*acc)[4]) {
    #pragma unroll
    for (int kk = 0; kk < 2; ++kk) {
        short8 a[4], b[4];
        int u = kk * 4 + kg;
        #pragma unroll
        for (int i = 0; i < 4; ++i) {
            int ra = wr * 64 + i * 16 + c;
            a[i] = *(const short8*)(rA + (ra >> 3) * CHUNK +
                                    (ra & 7) * 128 + u * 16);
            int rb = wc * 64 + i * 16 + c;
            b[i] = *(const short8*)(rB + (rb >> 3) * CHUNK +
                                    (rb & 7) * 128 + u * 16);
        }
        #pragma unroll
        for (int i = 0; i < 4; ++i)
            #pragma unroll
            for (int j = 0; j < 4; ++j)
                acc[i][j] = __builtin_amdgcn_mfma_f32_16x16x32_bf16(
                    a[i], b[j], acc[i][j], 0, 0, 0);
    }
}

#define WAITV8 asm volatile("s_waitcnt vmcnt(8)" ::: "memory")
#define WAITV0 asm volatile("s_waitcnt vmcnt(0)" ::: "memory")
#define SBAR   __builtin_amdgcn_s_barrier()

// ----------------- split: normalize + single bf16 (h) conversion ------------
__global__ __launch_bounds__(256) void split_h_kernel(
    const float* __restrict__ base, const float* __restrict__ real,
    ushort_t* __restrict__ Ah, ushort_t* __restrict__ Bh,
    float* __restrict__ inv) {
    int rid  = blockIdx.x * 4 + (threadIdx.x >> 6);
    int lane = threadIdx.x & 63;
    bool isA = rid < NB;
    int  row = isA ? rid : rid - NB;
    const float* src = isA ? base + (size_t)row * KDIM : real + (size_t)row * KDIM;
    float4 v = *(const float4*)(src + lane * 4);
    float ss = v.x * v.x + v.y * v.y + v.z * v.z + v.w * v.w;
    #pragma unroll
    for (int off = 32; off > 0; off >>= 1) ss += __shfl_xor(ss, off);
    float invn = 1.0f / fmaxf(sqrtf(ss), 1e-12f);

    ushort4 h4 = make_ushort4(f2bf(v.x * invn), f2bf(v.y * invn),
                              f2bf(v.z * invn), f2bf(v.w * invn));
    *(ushort4*)((isA ? Ah : Bh) + (size_t)row * KDIM + lane * 4) = h4;
    if (lane == 0) inv[rid] = invn;
}

// --------------------- bf16 MFMA GEMM (K=256) + per-block top-4 keys --------
// block 256 thr = 4 waves (2x2), tile 128x128, BK=64, 4 K-iterations.
// Double-buffered padded-chunk LDS (R10 base) with COUNTED vmcnt + raw
// s_barrier: prefetched tile's loads stay in flight across barriers
// (T4; the __syncthreads vmcnt(0) drain was the ~300cy/iter exposed cost).
// Epilogue: packed-key (val24<<7 | col7) u32 max-extract, DPP row-max.
__global__ __launch_bounds__(256) void mfma_topk_kernel(
    const ushort_t* __restrict__ Ah, const ushort_t* __restrict__ Bh,
    unsigned* __restrict__ Pk) {
    __shared__ char sA0[16 * CHUNK];
    __shared__ char sB0[16 * CHUNK];
    __shared__ char sA1[16 * CHUNK];
    __shared__ char sB1[16 * CHUNK];

    const int tid  = threadIdx.x;
    const int lane = tid & 63;
    const int w    = tid >> 6;
    const int wr   = w >> 1, wc = w & 1;
    const int c    = lane & 15;       // frag col/row-in-16
    const int kg   = lane >> 4;       // frag k-group (0..3)
    const int lr8  = lane >> 3;       // staging: row within 8-row chunk
    const int ud   = lane & 7;        // staging: 16B slot within row (linear)

    // ---- bijective XCD supertile remap: 8192 blocks = 8 XCD x 16 st x 8x8 --
    int lin = blockIdx.y * 64 + blockIdx.x;     // gridDim = (64, 128)
    int xcd = lin & 7;
    int pos = lin >> 3;                          // 0..1023
    int gg  = xcd * 1024 + pos;                  // chunked per-XCD range
    int st  = gg >> 6, in8 = gg & 63;            // supertile id, pos within
    int my  = ((st >> 3) << 3) + (in8 >> 3);     // 0..127 row tile
    int nx  = ((st & 7) << 3) + (in8 & 7);       // 0..63  col tile
    const int m0 = my * 128;
    const int n0 = nx * 128;

    f32x4 acc[4][4];
    #pragma unroll
    for (int i = 0; i < 4; ++i)
        #pragma unroll
        for (int j = 0; j < 4; ++j) acc[i][j] = (f32x4){0.f, 0.f, 0.f, 0.f};

    // ---- pipelined K-loop, straight-line (per-thread vmcnt audit in notes) -
    issue_tile(Ah, Bh, m0, n0, 0,   w, lr8, ud, sA0, sB0);   // t0 -> buf0
    issue_tile(Ah, Bh, m0, n0, 64,  w, lr8, ud, sA1, sB1);   // t1 -> buf1
    WAITV8; SBAR;                         // t0 resident (t1 in flight)
    compute_tile(sA0, sB0, wr, wc, c, kg, acc);
    SBAR;                                 // all waves done reading buf0
    issue_tile(Ah, Bh, m0, n0, 128, w, lr8, ud, sA0, sB0);   // t2 -> buf0
    WAITV8; SBAR;                         // t1 resident (t2 in flight)
    compute_tile(sA1, sB1, wr, wc, c, kg, acc);
    SBAR;                                 // all waves done reading buf1
    issue_tile(Ah, Bh, m0, n0, 192, w, lr8, ud, sA1, sB1);   // t3 -> buf1
    WAITV8; SBAR;                         // t2 resident (t3 in flight)
    compute_tile(sA0, sB0, wr, wc, c, kg, acc);
    WAITV0; SBAR;                         // t3 resident
    compute_tile(sA1, sB1, wr, wc, c, kg, acc);

    // ---- per-row top-4 keys over this block's 128 cols ----
    __syncthreads();                       // full drain; reuse LDS below
    unsigned* mk = (unsigned*)sA0;         // [128][2][4] keys (LDS reuse)
    #pragma unroll
    for (int i = 0; i < 4; ++i) {
        #pragma unroll
        for (int r = 0; r < 4; ++r) {
            unsigned k0 = ((__float_as_uint(acc[i][0][r] + 2.0f) - 0x3F800000u) << 7)
                          | (unsigned)(wc * 64 + 0 * 16 + c);
            unsigned k1 = ((__float_as_uint(acc[i][1][r] + 2.0f) - 0x3F800000u) << 7)
                          | (unsigned)(wc * 64 + 1 * 16 + c);
            unsigned k2 = ((__float_as_uint(acc[i][2][r] + 2.0f) - 0x3F800000u) << 7)
                          | (unsigned)(wc * 64 + 2 * 16 + c);
            unsigned k3 = ((__float_as_uint(acc[i][3][r] + 2.0f) - 0x3F800000u) << 7)
                          | (unsigned)(wc * 64 + 3 * 16 + c);
            unsigned top[4];
            #pragma unroll
            for (int p = 0; p < 4; ++p) {
                unsigned m01 = k0 > k1 ? k0 : k1;
                unsigned m23 = k2 > k3 ? k2 : k3;
                unsigned m   = m01 > m23 ? m01 : m23;
                m = rowmax16(m);           // VALU DPP, no DS ops
                top[p] = m;
                k0 = (k0 == m) ? 0u : k0;
                k1 = (k1 == m) ? 0u : k1;
                k2 = (k2 == m) ? 0u : k2;
                k3 = (k3 == m) ? 0u : k3;
            }
            if (c == 0) {
                int row = wr * 64 + i * 16 + kg * 4 + r;
                *(uint4*)&mk[(row * 2 + wc) * 4] =
                    make_uint4(top[0], top[1], top[2], top[3]);
            }
        }
    }
    __syncthreads();
    if (tid < 128) {
        unsigned e[8];
        *(uint4*)&e[0] = *(const uint4*)&mk[tid * 8];
        *(uint4*)&e[4] = *(const uint4*)&mk[tid * 8 + 4];
        unsigned top[4];
        #pragma unroll
        for (int p = 0; p < 4; ++p) {
            unsigned m = e[0];
            #pragma unroll
            for (int q = 1; q < 8; ++q) m = e[q] > m ? e[q] : m;
            top[p] = m;
            #pragma unroll
            for (int q = 0; q < 8; ++q) e[q] = (e[q] == m) ? 0u : e[q];
        }
        size_t o = (size_t)(m0 + tid) * 256 + nx * 4;   // [row][64 blocks][4]
        *(uint4*)&Pk[o] = make_uint4(top[0], top[1], top[2], top[3]);
    }
}

// ---- stage-2: u32-ekey butterfly -> global top-8, exact f32 rerank of 8 ----
// ekey = val19 << 13 | (8191 - idx): monotone (quant 7.6e-6 << top-8 spread,
// rerank-protected), unique via idx bits; 1-shfl butterfly steps (vs u64's 2).
__global__ __launch_bounds__(256) void merge8_kernel(
    const unsigned* __restrict__ Pk,
    const float* __restrict__ base, const float* __restrict__ real,
    const float* __restrict__ inv, int* __restrict__ out) {
    int row  = blockIdx.x * 4 + (threadIdx.x >> 6);
    int lane = threadIdx.x & 63;
    uint4 kv = *(const uint4*)(Pk + (size_t)row * 256 + lane * 4);

    unsigned k[4];
    {
        unsigned kk[4] = {kv.x, kv.y, kv.z, kv.w};
        #pragma unroll
        for (int e = 0; e < 4; ++e) {
            int idx = lane * 128 + (int)(kk[e] & 127u);
            k[e] = ((kk[e] >> 12) << 13) | (unsigned)(8191 - idx);
        }
    }

    int cnd[8];
    #pragma unroll
    for (int p = 0; p < 8; ++p) {
        unsigned m01 = k[0] > k[1] ? k[0] : k[1];
        unsigned m23 = k[2] > k[3] ? k[2] : k[3];
        unsigned m   = m01 > m23 ? m01 : m23;
        #pragma unroll
        for (int mask = 1; mask <= 32; mask <<= 1) {
            unsigned om = (unsigned)__shfl_xor((int)m, mask);
            m = om > m ? om : m;
        }
        cnd[p] = 8191 - (int)(m & 8191u);
        #pragma unroll
        for (int e = 0; e < 4; ++e) k[e] = (k[e] == m) ? 0u : k[e];
    }

    // exact f32 re-rank of the 8 candidates (one per lane 0..7)
    int cand = cnd[0];
    #pragma unroll
    for (int l = 1; l < 8; ++l) cand = (lane == l) ? cnd[l] : cand;
    float s = 0.0f;
    if (lane < 8) {
        const float* a = base + (size_t)row  * KDIM;
        const float* b = real + (size_t)cand * KDIM;
        float ia = inv[row], ib = inv[NB + cand];
        #pragma unroll 4
        for (int kq = 0; kq < KDIM; kq += 4) {
            float4 av = *(const float4*)(a + kq);
            float4 bv = *(const float4*)(b + kq);
            s = fmaf(av.x * ia, bv.x * ib, s);
            s = fmaf(av.y * ia, bv.y * ib, s);
            s = fmaf(av.z * ia, bv.z * ib, s);
            s = fmaf(av.w * ia, bv.w * ib, s);
        }
    }
    float fv0 = -3.0e38f, fv1 = -3.0e38f, fv2 = -3.0e38f;
    int   fi0 = 0x7fffffff, fi1 = 0x7fffffff, fi2 = 0x7fffffff;
    #pragma unroll
    for (int l = 0; l < 8; ++l) {
        float sv = __shfl(s, l);
        int   si = __shfl(cand, l);
        ins3(sv, si, fv0, fi0, fv1, fi1, fv2, fi2);
    }
    if (lane == 0) {
        out[row * 3 + 0] = fi0;
        out[row * 3 + 1] = fi1;
        out[row * 3 + 2] = fi2;
    }
}

// ======================= fallback (round-1 f32 path) ========================
__global__ __launch_bounds__(256) void norm_kernel(const float* __restrict__ base,
                                                   const float* __restrict__ real,
                                                   float* __restrict__ inv) {
    int rid  = blockIdx.x * 4 + (threadIdx.x >> 6);
    int lane = threadIdx.x & 63;
    if (rid >= NB + NR) return;
    const float* src = (rid < NB) ? (base + (size_t)rid * KDIM)
                                  : (real + (size_t)(rid - NB) * KDIM);
    float4 v = *(const float4*)(src + lane * 4);
    float ss = v.x * v.x + v.y * v.y + v.z * v.z + v.w * v.w;
    #pragma unroll
    for (int off = 32; off > 0; off >>= 1) ss += __shfl_xor(ss, off);
    if (lane == 0) inv[rid] = 1.0f / fmaxf(sqrtf(ss), 1e-12f);
}

#define DOT(i, j, av, bv)                                                      \
    acc[i][j] = fmaf(av.x, bv.x, acc[i][j]);                                   \
    acc[i][j] = fmaf(av.y, bv.y, acc[i][j]);                                   \
    acc[i][j] = fmaf(av.z, bv.z, acc[i][j]);                                   \
    acc[i][j] = fmaf(av.w, bv.w, acc[i][j]);

__global__ __launch_bounds__(256) void simtopk_kernel(
    const float* __restrict__ A, const float* __restrict__ B,
    const float* __restrict__ invA, const float* __restrict__ invB,
    int* __restrict__ out) {
    __shared__ float sA[64 * 68];
    __shared__ float sB[64 * 68];
    const int tid = threadIdx.x;
    const int tx  = tid & 15;
    const int ty4 = (tid >> 4) << 2;
    const int m0  = blockIdx.x * 64;
    float t3v[4][3];
    int   t3i[4][3];
    #pragma unroll
    for (int i = 0; i < 4; ++i)
        #pragma unroll
        for (int s = 0; s < 3; ++s) { t3v[i][s] = -3.0e38f; t3i[i][s] = 0x7fffffff; }
    for (int nn0 = 0; nn0 < NR; nn0 += 64) {
        float acc[4][4] = {{0.f}};
        for (int kc = 0; kc < KDIM; kc += 64) {
            __syncthreads();
            #pragma unroll
            for (int p = 0; p < 4; ++p) {
                int f = tid + (p << 8), row = f >> 4, c4 = (f & 15) << 2;
                float4 va = *(const float4*)(A + (size_t)(m0 + row) * KDIM + kc + c4);
                float  sa = invA[m0 + row];
                va.x *= sa; va.y *= sa; va.z *= sa; va.w *= sa;
                *(float4*)&sA[row * 68 + c4] = va;
                float4 vb = *(const float4*)(B + (size_t)(nn0 + row) * KDIM + kc + c4);
                float  sb = invB[nn0 + row];
                vb.x *= sb; vb.y *= sb; vb.z *= sb; vb.w *= sb;
                *(float4*)&sB[row * 68 + c4] = vb;
            }
            __syncthreads();
            #pragma unroll
            for (int k = 0; k < 64; k += 4) {
                float4 a0 = *(const float4*)&sA[(ty4 + 0) * 68 + k];
                float4 a1 = *(const float4*)&sA[(ty4 + 1) * 68 + k];
                float4 a2 = *(const float4*)&sA[(ty4 + 2) * 68 + k];
                float4 a3 = *(const float4*)&sA[(ty4 + 3) * 68 + k];
                float4 b0 = *(const float4*)&sB[(tx +  0) * 68 + k];
                float4 b1 = *(const float4*)&sB[(tx + 16) * 68 + k];
                float4 b2 = *(const float4*)&sB[(tx + 32) * 68 + k];
                float4 b3 = *(const float4*)&sB[(tx + 48) * 68 + k];
                DOT(0,0,a0,b0) DOT(0,1,a0,b1) DOT(0,2,a0,b2) DOT(0,3,a0,b3)
                DOT(1,0,a1,b0) DOT(1,1,a1,b1) DOT(1,2,a1,b2) DOT(1,3,a1,b3)
                DOT(2,0,a2,b0) DOT(2,1,a2,b1) DOT(2,2,a2,b2) DOT(2,3,a2,b3)
                DOT(3,0,a3,b0) DOT(3,1,a3,b1) DOT(3,2,a3,b2) DOT(3,3,a3,b3)
            }
        }
        #pragma unroll
        for (int i = 0; i < 4; ++i)
            #pragma unroll
            for (int j = 0; j < 4; ++j)
                ins3f(acc[i][j], nn0 + tx + 16 * j, t3v[i], t3i[i]);
    }
    __syncthreads();
    float* mv = sA;
    int*   mi = (int*)sB;
    #pragma unroll
    for (int i = 0; i < 4; ++i)
        #pragma unroll
        for (int s = 0; s < 3; ++s) {
            mv[(ty4 + i) * 48 + tx * 3 + s] = t3v[i][s];
            mi[(ty4 + i) * 48 + tx * 3 + s] = t3i[i][s];
        }
    __syncthreads();
    if (tid < 64) {
        float v0 = -3.0e38f, v1 = -3.0e38f, v2 = -3.0e38f;
        int   i0 = 0x7fffffff, i1 = 0x7fffffff, i2 = 0x7fffffff;
        for (int e = 0; e < 48; ++e)
            ins3(mv[tid * 48 + e], mi[tid * 48 + e], v0, i0, v1, i1, v2, i2);
        out[(m0 + tid) * 3 + 0] = i0;
        out[(m0 + tid) * 3 + 1] = i1;
        out[(m0 + tid) * 3 + 2] = i2;
    }
}

// ============================================================== launcher ====
extern "C" void kernel_launch(void* const* d_in, const int* in_sizes, int n_in,
                              void* d_out, int out_size, void* d_ws, size_t ws_size,
                              hipStream_t stream) {
    const float* base = (const float*)d_in[0];
    const float* real = (const float*)d_in[1];
    int* out = (int*)d_out;

    const size_t szAh  = (size_t)NB * KDIM * 2;      // 8.4 MB
    const size_t szBh  = (size_t)NR * KDIM * 2;      // 4.2 MB
    const size_t szPk  = (size_t)NB * 256 * 4;       // 16.8 MB
    const size_t szInv = (size_t)(NB + NR) * 4;      // 0.1 MB
    const size_t need  = szAh + szBh + szPk + szInv;

    if (ws_size >= need) {
        char* p = (char*)d_ws;
        ushort_t* Ah  = (ushort_t*)(p);
        ushort_t* Bh  = (ushort_t*)(p + szAh);
        unsigned* Pk  = (unsigned*)(p + szAh + szBh);
        float*    inv = (float*)   (p + szAh + szBh + szPk);

        hipLaunchKernelGGL(split_h_kernel, dim3((NB + NR) / 4), dim3(256), 0, stream,
                           base, real, Ah, Bh, inv);
        hipLaunchKernelGGL(mfma_topk_kernel, dim3(NR / 128, NB / 128), dim3(256), 0,
                           stream, Ah, Bh, Pk);
        hipLaunchKernelGGL(merge8_kernel, dim3(NB / 4), dim3(256), 0, stream,
                           Pk, base, real, inv, out);
    } else {
        float* inv = (float*)d_ws;
        hipLaunchKernelGGL(norm_kernel, dim3((NB + NR) / 4), dim3(256), 0, stream,
                           base, real, inv);
        hipLaunchKernelGGL(simtopk_kernel, dim3(NB / 64), dim3(256), 0, stream,
                           base, real, inv, inv + NB, out);
    }
}

// Round 15
// 166.626 us; speedup vs baseline: 1.3955x; 1.2565x over previous
//
#include <hip/hip_runtime.h>

#define KDIM 256
#define NB 16384
#define NR 8192
#define CHUNK 1088            // 1024B data (16 rows x 64B i8) + 64B pad

typedef unsigned short ushort_t;
typedef unsigned char uchar_t;
typedef __attribute__((ext_vector_type(4))) int i32x4;

// ---------------------------------------------------------------- helpers ---
__device__ __forceinline__ void gload16(const void* g, void* l) {
    __builtin_amdgcn_global_load_lds(
        (const __attribute__((address_space(1))) void*)g,
        (__attribute__((address_space(3))) void*)l, 16, 0, 0);
}
// 16-lane all-reduce max on the VALU pipe: v_max through DPP row rotations
__device__ __forceinline__ unsigned rowmax16(unsigned m) {
    unsigned t;
    t = (unsigned)__builtin_amdgcn_update_dpp(0, (int)m, 0x121, 0xf, 0xf, true);
    m = t > m ? t : m;
    t = (unsigned)__builtin_amdgcn_update_dpp(0, (int)m, 0x122, 0xf, 0xf, true);
    m = t > m ? t : m;
    t = (unsigned)__builtin_amdgcn_update_dpp(0, (int)m, 0x124, 0xf, 0xf, true);
    m = t > m ? t : m;
    t = (unsigned)__builtin_amdgcn_update_dpp(0, (int)m, 0x128, 0xf, 0xf, true);
    m = t > m ? t : m;
    return m;
}
// branchless insert into sorted top-3 (v desc, idx asc on ties)
__device__ __forceinline__ void ins3(float v, int idx,
                                     float& v0, int& i0, float& v1, int& i1,
                                     float& v2, int& i2) {
    bool b0 = (v > v0) | ((v == v0) & (idx < i0));
    bool b1 = (v > v1) | ((v == v1) & (idx < i1));
    bool b2 = (v > v2) | ((v == v2) & (idx < i2));
    float nv2 = b1 ? v1 : (b2 ? v : v2);
    int   ni2 = b1 ? i1 : (b2 ? idx : i2);
    float nv1 = b0 ? v0 : (b1 ? v : v1);
    int   ni1 = b0 ? i0 : (b1 ? idx : i1);
    float nv0 = b0 ? v : v0;
    int   ni0 = b0 ? idx : i0;
    v0 = nv0; i0 = ni0; v1 = nv1; i1 = ni1; v2 = nv2; i2 = ni2;
}
__device__ __forceinline__ void ins3f(float v, int idx, float* tv, int* ti) {
    ins3(v, idx, tv[0], ti[0], tv[1], ti[1], tv[2], ti[2]);
}

// i8 GEMM tile helpers. Staging: chunk = 16 rows x 64B; source slice index
// s = p ^ ((row>>1)&3) (permutes WITHIN one 64B row -> coalescing kept);
// frag reads then hit banks 16(c&1)+4(g^((c>>1)&3)) -> all 32 banks, 2-way.
__device__ __forceinline__ void issue_tile(
    const uchar_t* __restrict__ Ai, const uchar_t* __restrict__ Bi,
    int m0, int n0, int kc, int w, int lane, char* dA, char* dB) {
    int lr  = lane >> 2;                       // row within 16-row chunk
    int sl  = (lane & 3) ^ ((lane >> 3) & 3);  // pre-swizzled source slice
    #pragma unroll
    for (int q = 0; q < 2; ++q) {
        int cq = w * 2 + q;                    // chunk id 0..7
        gload16(Ai + (size_t)(m0 + cq * 16 + lr) * KDIM + kc + sl * 16,
                dA + cq * CHUNK);
        gload16(Bi + (size_t)(n0 + cq * 16 + lr) * KDIM + kc + sl * 16,
                dB + cq * CHUNK);
    }
}
__device__ __forceinline__ void compute_tile(
    const char* rA, const char* rB, int wr, int wc, int c, int kg,
    i32x4 (*acc)[4]) {
    i32x4 a[4], b[4];
    #pragma unroll
    for (int i = 0; i < 4; ++i) {
        int ra = wr * 64 + i * 16 + c;
        a[i] = *(const i32x4*)(rA + (ra >> 4) * CHUNK + (ra & 15) * 64 +
                               ((kg ^ ((ra >> 1) & 3)) << 4));
        int rb = wc * 64 + i * 16 + c;
        b[i] = *(const i32x4*)(rB + (rb >> 4) * CHUNK + (rb & 15) * 64 +
                               ((kg ^ ((rb >> 1) & 3)) << 4));
    }
    #pragma unroll
    for (int i = 0; i < 4; ++i)
        #pragma unroll
        for (int j = 0; j < 4; ++j)
            acc[i][j] = __builtin_amdgcn_mfma_i32_16x16x64_i8(
                a[i], b[j], acc[i][j], 0, 0, 0);
}

#define WAITV4 asm volatile("s_waitcnt vmcnt(4)" ::: "memory")
#define WAITV0 asm volatile("s_waitcnt vmcnt(0)" ::: "memory")
#define SBAR   __builtin_amdgcn_s_barrier()

// -------- split: normalize + per-row i8 quantization (q = rint(127 x/max)) --
__global__ __launch_bounds__(256) void split_q_kernel(
    const float* __restrict__ base, const float* __restrict__ real,
    uchar_t* __restrict__ Ai, uchar_t* __restrict__ Bi,
    float* __restrict__ inv, float* __restrict__ sb) {
    int rid  = blockIdx.x * 4 + (threadIdx.x >> 6);
    int lane = threadIdx.x & 63;
    bool isA = rid < NB;
    int  row = isA ? rid : rid - NB;
    const float* src = isA ? base + (size_t)row * KDIM : real + (size_t)row * KDIM;
    float4 v = *(const float4*)(src + lane * 4);
    float ss = v.x * v.x + v.y * v.y + v.z * v.z + v.w * v.w;
    #pragma unroll
    for (int off = 32; off > 0; off >>= 1) ss += __shfl_xor(ss, off);
    float invn = 1.0f / fmaxf(sqrtf(ss), 1e-12f);

    float n0 = v.x * invn, n1 = v.y * invn, n2 = v.z * invn, n3 = v.w * invn;
    float am = fmaxf(fmaxf(fabsf(n0), fabsf(n1)), fmaxf(fabsf(n2), fabsf(n3)));
    #pragma unroll
    for (int off = 32; off > 0; off >>= 1) am = fmaxf(am, __shfl_xor(am, off));
    float qs = 127.0f / am;
    int q0 = (int)rintf(n0 * qs), q1 = (int)rintf(n1 * qs);
    int q2 = (int)rintf(n2 * qs), q3 = (int)rintf(n3 * qs);
    unsigned w32 = (q0 & 0xff) | ((q1 & 0xff) << 8) |
                   ((q2 & 0xff) << 16) | ((unsigned)(q3 & 0xff) << 24);
    *(unsigned*)((isA ? Ai : Bi) + (size_t)row * KDIM + lane * 4) = w32;
    if (lane == 0) {
        inv[rid] = invn;
        if (!isA) sb[row] = am / 127.0f;   // column scale for ranking keys
    }
}

// --------------------- i8 MFMA GEMM (K=256) + per-block top-4 keys ----------
// block 256 thr = 4 waves (2x2), tile 128x128, BK=64 (one 16x16x64 MFMA per
// (i,j) per iter), double-buffered, counted vmcnt(4) pipeline (R14 shape).
// Epilogue: v = (float)D * sb[col]; key = (as_uint(v+8192)-0x45B00000)<<7|col.
__global__ __launch_bounds__(256) void mfma_topk_kernel(
    const uchar_t* __restrict__ Ai, const uchar_t* __restrict__ Bi,
    const float* __restrict__ sb, unsigned* __restrict__ Pk) {
    __shared__ char sA0[8 * CHUNK];
    __shared__ char sB0[8 * CHUNK];
    __shared__ char sA1[8 * CHUNK];
    __shared__ char sB1[8 * CHUNK];

    const int tid  = threadIdx.x;
    const int lane = tid & 63;
    const int w    = tid >> 6;
    const int wr   = w >> 1, wc = w & 1;
    const int c    = lane & 15;       // frag col/row-in-16
    const int kg   = lane >> 4;       // frag k-slice (0..3), 16B each

    // ---- bijective XCD supertile remap: 8192 blocks = 8 XCD x 16 st x 8x8 --
    int lin = blockIdx.y * 64 + blockIdx.x;     // gridDim = (64, 128)
    int xcd = lin & 7;
    int pos = lin >> 3;                          // 0..1023
    int gg  = xcd * 1024 + pos;                  // chunked per-XCD range
    int st  = gg >> 6, in8 = gg & 63;            // supertile id, pos within
    int my  = ((st >> 3) << 3) + (in8 >> 3);     // 0..127 row tile
    int nx  = ((st & 7) << 3) + (in8 & 7);       // 0..63  col tile
    const int m0 = my * 128;
    const int n0 = nx * 128;

    i32x4 acc[4][4];
    #pragma unroll
    for (int i = 0; i < 4; ++i)
        #pragma unroll
        for (int j = 0; j < 4; ++j) acc[i][j] = (i32x4){0, 0, 0, 0};

    // ---- pipelined K-loop (4 gload16/wave/tile -> counted vmcnt(4)) -------
    issue_tile(Ai, Bi, m0, n0, 0,   w, lane, sA0, sB0);   // t0 -> buf0
    issue_tile(Ai, Bi, m0, n0, 64,  w, lane, sA1, sB1);   // t1 -> buf1
    WAITV4; SBAR;                         // t0 resident (t1 in flight)
    compute_tile(sA0, sB0, wr, wc, c, kg, acc);
    SBAR;                                 // all waves done reading buf0
    issue_tile(Ai, Bi, m0, n0, 128, w, lane, sA0, sB0);   // t2 -> buf0
    WAITV4; SBAR;                         // t1 resident (t2 in flight)
    compute_tile(sA1, sB1, wr, wc, c, kg, acc);
    SBAR;                                 // all waves done reading buf1
    issue_tile(Ai, Bi, m0, n0, 192, w, lane, sA1, sB1);   // t3 -> buf1
    WAITV4; SBAR;                         // t2 resident (t3 in flight)
    compute_tile(sA0, sB0, wr, wc, c, kg, acc);
    WAITV0; SBAR;                         // t3 resident
    compute_tile(sA1, sB1, wr, wc, c, kg, acc);

    // ---- epilogue: column scales (outside counted region) ------------------
    float sbj[4];
    #pragma unroll
    for (int j = 0; j < 4; ++j) sbj[j] = sb[n0 + wc * 64 + j * 16 + c];

    // ---- per-row top-4 keys over this block's 128 cols ----
    __syncthreads();                       // full drain; reuse LDS below
    unsigned* mk = (unsigned*)sA0;         // [128][2][4] keys (4KB)
    #pragma unroll
    for (int i = 0; i < 4; ++i) {
        #pragma unroll
        for (int r = 0; r < 4; ++r) {
            unsigned k0 = ((__float_as_uint((float)acc[i][0][r] * sbj[0] + 8192.0f)
                            - 0x45B00000u) << 7) | (unsigned)(wc * 64 + 0 * 16 + c);
            unsigned k1 = ((__float_as_uint((float)acc[i][1][r] * sbj[1] + 8192.0f)
                            - 0x45B00000u) << 7) | (unsigned)(wc * 64 + 1 * 16 + c);
            unsigned k2 = ((__float_as_uint((float)acc[i][2][r] * sbj[2] + 8192.0f)
                            - 0x45B00000u) << 7) | (unsigned)(wc * 64 + 2 * 16 + c);
            unsigned k3 = ((__float_as_uint((float)acc[i][3][r] * sbj[3] + 8192.0f)
                            - 0x45B00000u) << 7) | (unsigned)(wc * 64 + 3 * 16 + c);
            unsigned top[4];
            #pragma unroll
            for (int p = 0; p < 4; ++p) {
                unsigned m01 = k0 > k1 ? k0 : k1;
                unsigned m23 = k2 > k3 ? k2 : k3;
                unsigned m   = m01 > m23 ? m01 : m23;
                m = rowmax16(m);           // VALU DPP, no DS ops
                top[p] = m;
                k0 = (k0 == m) ? 0u : k0;
                k1 = (k1 == m) ? 0u : k1;
                k2 = (k2 == m) ? 0u : k2;
                k3 = (k3 == m) ? 0u : k3;
            }
            if (c == 0) {
                int row = wr * 64 + i * 16 + kg * 4 + r;
                *(uint4*)&mk[(row * 2 + wc) * 4] =
                    make_uint4(top[0], top[1], top[2], top[3]);
            }
        }
    }
    __syncthreads();
    if (tid < 128) {
        unsigned e[8];
        *(uint4*)&e[0] = *(const uint4*)&mk[tid * 8];
        *(uint4*)&e[4] = *(const uint4*)&mk[tid * 8 + 4];
        unsigned top[4];
        #pragma unroll
        for (int p = 0; p < 4; ++p) {
            unsigned m = e[0];
            #pragma unroll
            for (int q = 1; q < 8; ++q) m = e[q] > m ? e[q] : m;
            top[p] = m;
            #pragma unroll
            for (int q = 0; q < 8; ++q) e[q] = (e[q] == m) ? 0u : e[q];
        }
        size_t o = (size_t)(m0 + tid) * 256 + nx * 4;   // [row][64 blocks][4]
        *(uint4*)&Pk[o] = make_uint4(top[0], top[1], top[2], top[3]);
    }
}

// ---- stage-2: u32-ekey butterfly -> global top-8, exact f32 rerank of 8 ----
// ekey = val-bits<<13 | (8191 - idx): monotone, unique via idx bits.
__global__ __launch_bounds__(256) void merge8_kernel(
    const unsigned* __restrict__ Pk,
    const float* __restrict__ base, const float* __restrict__ real,
    const float* __restrict__ inv, int* __restrict__ out) {
    int row  = blockIdx.x * 4 + (threadIdx.x >> 6);
    int lane = threadIdx.x & 63;
    uint4 kv = *(const uint4*)(Pk + (size_t)row * 256 + lane * 4);

    unsigned k[4];
    {
        unsigned kk[4] = {kv.x, kv.y, kv.z, kv.w};
        #pragma unroll
        for (int e = 0; e < 4; ++e) {
            int idx = lane * 128 + (int)(kk[e] & 127u);
            k[e] = ((kk[e] >> 12) << 13) | (unsigned)(8191 - idx);
        }
    }

    int cnd[8];
    #pragma unroll
    for (int p = 0; p < 8; ++p) {
        unsigned m01 = k[0] > k[1] ? k[0] : k[1];
        unsigned m23 = k[2] > k[3] ? k[2] : k[3];
        unsigned m   = m01 > m23 ? m01 : m23;
        #pragma unroll
        for (int mask = 1; mask <= 32; mask <<= 1) {
            unsigned om = (unsigned)__shfl_xor((int)m, mask);
            m = om > m ? om : m;
        }
        cnd[p] = 8191 - (int)(m & 8191u);
        #pragma unroll
        for (int e = 0; e < 4; ++e) k[e] = (k[e] == m) ? 0u : k[e];
    }

    // exact f32 re-rank of the 8 candidates (one per lane 0..7)
    int cand = cnd[0];
    #pragma unroll
    for (int l = 1; l < 8; ++l) cand = (lane == l) ? cnd[l] : cand;
    float s = 0.0f;
    if (lane < 8) {
        const float* a = base + (size_t)row  * KDIM;
        const float* b = real + (size_t)cand * KDIM;
        float ia = inv[row], ib = inv[NB + cand];
        #pragma unroll 4
        for (int kq = 0; kq < KDIM; kq += 4) {
            float4 av = *(const float4*)(a + kq);
            float4 bv = *(const float4*)(b + kq);
            s = fmaf(av.x * ia, bv.x * ib, s);
            s = fmaf(av.y * ia, bv.y * ib, s);
            s = fmaf(av.z * ia, bv.z * ib, s);
            s = fmaf(av.w * ia, bv.w * ib, s);
        }
    }
    float fv0 = -3.0e38f, fv1 = -3.0e38f, fv2 = -3.0e38f;
    int   fi0 = 0x7fffffff, fi1 = 0x7fffffff, fi2 = 0x7fffffff;
    #pragma unroll
    for (int l = 0; l < 8; ++l) {
        float sv = __shfl(s, l);
        int   si = __shfl(cand, l);
        ins3(sv, si, fv0, fi0, fv1, fi1, fv2, fi2);
    }
    if (lane == 0) {
        out[row * 3 + 0] = fi0;
        out[row * 3 + 1] = fi1;
        out[row * 3 + 2] = fi2;
    }
}

// ======================= fallback (round-1 f32 path) ========================
__global__ __launch_bounds__(256) void norm_kernel(const float* __restrict__ base,
                                                   const float* __restrict__ real,
                                                   float* __restrict__ inv) {
    int rid  = blockIdx.x * 4 + (threadIdx.x >> 6);
    int lane = threadIdx.x & 63;
    if (rid >= NB + NR) return;
    const float* src = (rid < NB) ? (base + (size_t)rid * KDIM)
                                  : (real + (size_t)(rid - NB) * KDIM);
    float4 v = *(const float4*)(src + lane * 4);
    float ss = v.x * v.x + v.y * v.y + v.z * v.z + v.w * v.w;
    #pragma unroll
    for (int off = 32; off > 0; off >>= 1) ss += __shfl_xor(ss, off);
    if (lane == 0) inv[rid] = 1.0f / fmaxf(sqrtf(ss), 1e-12f);
}

#define DOT(i, j, av, bv)                                                      \
    acc[i][j] = fmaf(av.x, bv.x, acc[i][j]);                                   \
    acc[i][j] = fmaf(av.y, bv.y, acc[i][j]);                                   \
    acc[i][j] = fmaf(av.z, bv.z, acc[i][j]);                                   \
    acc[i][j] = fmaf(av.w, bv.w, acc[i][j]);

__global__ __launch_bounds__(256) void simtopk_kernel(
    const float* __restrict__ A, const float* __restrict__ B,
    const float* __restrict__ invA, const float* __restrict__ invB,
    int* __restrict__ out) {
    __shared__ float sA[64 * 68];
    __shared__ float sB[64 * 68];
    const int tid = threadIdx.x;
    const int tx  = tid & 15;
    const int ty4 = (tid >> 4) << 2;
    const int m0  = blockIdx.x * 64;
    float t3v[4][3];
    int   t3i[4][3];
    #pragma unroll
    for (int i = 0; i < 4; ++i)
        #pragma unroll
        for (int s = 0; s < 3; ++s) { t3v[i][s] = -3.0e38f; t3i[i][s] = 0x7fffffff; }
    for (int nn0 = 0; nn0 < NR; nn0 += 64) {
        float acc[4][4] = {{0.f}};
        for (int kc = 0; kc < KDIM; kc += 64) {
            __syncthreads();
            #pragma unroll
            for (int p = 0; p < 4; ++p) {
                int f = tid + (p << 8), row = f >> 4, c4 = (f & 15) << 2;
                float4 va = *(const float4*)(A + (size_t)(m0 + row) * KDIM + kc + c4);
                float  sa = invA[m0 + row];
                va.x *= sa; va.y *= sa; va.z *= sa; va.w *= sa;
                *(float4*)&sA[row * 68 + c4] = va;
                float4 vb = *(const float4*)(B + (size_t)(nn0 + row) * KDIM + kc + c4);
                float  sb2 = invB[nn0 + row];
                vb.x *= sb2; vb.y *= sb2; vb.z *= sb2; vb.w *= sb2;
                *(float4*)&sB[row * 68 + c4] = vb;
            }
            __syncthreads();
            #pragma unroll
            for (int k = 0; k < 64; k += 4) {
                float4 a0 = *(const float4*)&sA[(ty4 + 0) * 68 + k];
                float4 a1 = *(const float4*)&sA[(ty4 + 1) * 68 + k];
                float4 a2 = *(const float4*)&sA[(ty4 + 2) * 68 + k];
                float4 a3 = *(const float4*)&sA[(ty4 + 3) * 68 + k];
                float4 b0 = *(const float4*)&sB[(tx +  0) * 68 + k];
                float4 b1 = *(const float4*)&sB[(tx + 16) * 68 + k];
                float4 b2 = *(const float4*)&sB[(tx + 32) * 68 + k];
                float4 b3 = *(const float4*)&sB[(tx + 48) * 68 + k];
                DOT(0,0,a0,b0) DOT(0,1,a0,b1) DOT(0,2,a0,b2) DOT(0,3,a0,b3)
                DOT(1,0,a1,b0) DOT(1,1,a1,b1) DOT(1,2,a1,b2) DOT(1,3,a1,b3)
                DOT(2,0,a2,b0) DOT(2,1,a2,b1) DOT(2,2,a2,b2) DOT(2,3,a2,b3)
                DOT(3,0,a3,b0) DOT(3,1,a3,b1) DOT(3,2,a3,b2) DOT(3,3,a3,b3)
            }
        }
        #pragma unroll
        for (int i = 0; i < 4; ++i)
            #pragma unroll
            for (int j = 0; j < 4; ++j)
                ins3f(acc[i][j], nn0 + tx + 16 * j, t3v[i], t3i[i]);
    }
    __syncthreads();
    float* mv = sA;
    int*   mi = (int*)sB;
    #pragma unroll
    for (int i = 0; i < 4; ++i)
        #pragma unroll
        for (int s = 0; s < 3; ++s) {
            mv[(ty4 + i) * 48 + tx * 3 + s] = t3v[i][s];
            mi[(ty4 + i) * 48 + tx * 3 + s] = t3i[i][s];
        }
    __syncthreads();
    if (tid < 64) {
        float v0 = -3.0e38f, v1 = -3.0e38f, v2 = -3.0e38f;
        int   i0 = 0x7fffffff, i1 = 0x7fffffff, i2 = 0x7fffffff;
        for (int e = 0; e < 48; ++e)
            ins3(mv[tid * 48 + e], mi[tid * 48 + e], v0, i0, v1, i1, v2, i2);
        out[(m0 + tid) * 3 + 0] = i0;
        out[(m0 + tid) * 3 + 1] = i1;
        out[(m0 + tid) * 3 + 2] = i2;
    }
}

// ============================================================== launcher ====
extern "C" void kernel_launch(void* const* d_in, const int* in_sizes, int n_in,
                              void* d_out, int out_size, void* d_ws, size_t ws_size,
                              hipStream_t stream) {
    const float* base = (const float*)d_in[0];
    const float* real = (const float*)d_in[1];
    int* out = (int*)d_out;

    const size_t szAi  = (size_t)NB * KDIM;          // 4.2 MB (i8)
    const size_t szBi  = (size_t)NR * KDIM;          // 2.1 MB (i8)
    const size_t szPk  = (size_t)NB * 256 * 4;       // 16.8 MB
    const size_t szInv = (size_t)(NB + NR) * 4;      // 0.1 MB
    const size_t szSb  = (size_t)NR * 4;             // 0.03 MB
    const size_t need  = szAi + szBi + szPk + szInv + szSb;

    if (ws_size >= need) {
        char* p = (char*)d_ws;
        uchar_t*  Ai  = (uchar_t*)(p);
        uchar_t*  Bi  = (uchar_t*)(p + szAi);
        unsigned* Pk  = (unsigned*)(p + szAi + szBi);
        float*    inv = (float*)   (p + szAi + szBi + szPk);
        float*    sb  = (float*)   (p + szAi + szBi + szPk + szInv);

        hipLaunchKernelGGL(split_q_kernel, dim3((NB + NR) / 4), dim3(256), 0, stream,
                           base, real, Ai, Bi, inv, sb);
        hipLaunchKernelGGL(mfma_topk_kernel, dim3(NR / 128, NB / 128), dim3(256), 0,
                           stream, Ai, Bi, sb, Pk);
        hipLaunchKernelGGL(merge8_kernel, dim3(NB / 4), dim3(256), 0, stream,
                           Pk, base, real, inv, out);
    } else {
        float* inv = (float*)d_ws;
        hipLaunchKernelGGL(norm_kernel, dim3((NB + NR) / 4), dim3(256), 0, stream,
                           base, real, inv);
        hipLaunchKernelGGL(simtopk_kernel, dim3(NB / 64), dim3(256), 0, stream,
                           base, real, inv, inv + NB, out);
    }
}

// Round 17
// 122.533 us; speedup vs baseline: 1.8977x; 1.3599x over previous
//
#include <hip/hip_runtime.h>

#define KDIM 256
#define NB 16384
#define NR 8192
#define CHUNK 1088            // 1024B data (16 rows x 64B i8) + 64B pad

typedef unsigned short ushort_t;
typedef unsigned char uchar_t;
typedef __attribute__((ext_vector_type(4))) int i32x4;

// ---------------------------------------------------------------- helpers ---
__device__ __forceinline__ void gload16(const void* g, void* l) {
    __builtin_amdgcn_global_load_lds(
        (const __attribute__((address_space(1))) void*)g,
        (__attribute__((address_space(3))) void*)l, 16, 0, 0);
}
// 16-lane all-reduce max on the VALU pipe: v_max through DPP row rotations
__device__ __forceinline__ unsigned rowmax16(unsigned m) {
    unsigned t;
    t = (unsigned)__builtin_amdgcn_update_dpp(0, (int)m, 0x121, 0xf, 0xf, true);
    m = t > m ? t : m;
    t = (unsigned)__builtin_amdgcn_update_dpp(0, (int)m, 0x122, 0xf, 0xf, true);
    m = t > m ? t : m;
    t = (unsigned)__builtin_amdgcn_update_dpp(0, (int)m, 0x124, 0xf, 0xf, true);
    m = t > m ? t : m;
    t = (unsigned)__builtin_amdgcn_update_dpp(0, (int)m, 0x128, 0xf, 0xf, true);
    m = t > m ? t : m;
    return m;
}
// branchless insert into sorted top-3 (v desc, idx asc on ties)
__device__ __forceinline__ void ins3(float v, int idx,
                                     float& v0, int& i0, float& v1, int& i1,
                                     float& v2, int& i2) {
    bool b0 = (v > v0) | ((v == v0) & (idx < i0));
    bool b1 = (v > v1) | ((v == v1) & (idx < i1));
    bool b2 = (v > v2) | ((v == v2) & (idx < i2));
    float nv2 = b1 ? v1 : (b2 ? v : v2);
    int   ni2 = b1 ? i1 : (b2 ? idx : i2);
    float nv1 = b0 ? v0 : (b1 ? v : v1);
    int   ni1 = b0 ? i0 : (b1 ? idx : i1);
    float nv0 = b0 ? v : v0;
    int   ni0 = b0 ? idx : i0;
    v0 = nv0; i0 = ni0; v1 = nv1; i1 = ni1; v2 = nv2; i2 = ni2;
}
__device__ __forceinline__ void ins3f(float v, int idx, float* tv, int* ti) {
    ins3(v, idx, tv[0], ti[0], tv[1], ti[1], tv[2], ti[2]);
}

// i8 GEMM tile helpers. Staging: chunk = 16 rows x 64B; source slice index
// s = p ^ ((row>>1)&3) (permutes WITHIN one 64B row -> coalescing kept);
// frag reads then hit banks 16(c&1)+4(g^((c>>1)&3)) -> all 32 banks, 2-way.
__device__ __forceinline__ void issue_tile(
    const uchar_t* __restrict__ Ai, const uchar_t* __restrict__ Bi,
    int m0, int n0, int kc, int w, int lane, char* dA, char* dB) {
    int lr  = lane >> 2;                       // row within 16-row chunk
    int sl  = (lane & 3) ^ ((lane >> 3) & 3);  // pre-swizzled source slice
    #pragma unroll
    for (int q = 0; q < 2; ++q) {
        int cq = w * 2 + q;                    // chunk id 0..7
        gload16(Ai + (size_t)(m0 + cq * 16 + lr) * KDIM + kc + sl * 16,
                dA + cq * CHUNK);
        gload16(Bi + (size_t)(n0 + cq * 16 + lr) * KDIM + kc + sl * 16,
                dB + cq * CHUNK);
    }
}
__device__ __forceinline__ void compute_tile(
    const char* rA, const char* rB, int wr, int wc, int c, int kg,
    i32x4 (*acc)[4]) {
    i32x4 a[4], b[4];
    #pragma unroll
    for (int i = 0; i < 4; ++i) {
        int ra = wr * 64 + i * 16 + c;
        a[i] = *(const i32x4*)(rA + (ra >> 4) * CHUNK + (ra & 15) * 64 +
                               ((kg ^ ((ra >> 1) & 3)) << 4));
        int rb = wc * 64 + i * 16 + c;
        b[i] = *(const i32x4*)(rB + (rb >> 4) * CHUNK + (rb & 15) * 64 +
                               ((kg ^ ((rb >> 1) & 3)) << 4));
    }
    #pragma unroll
    for (int i = 0; i < 4; ++i)
        #pragma unroll
        for (int j = 0; j < 4; ++j)
            acc[i][j] = __builtin_amdgcn_mfma_i32_16x16x64_i8(
                a[i], b[j], acc[i][j], 0, 0, 0);
}

#define WAITV4 asm volatile("s_waitcnt vmcnt(4)" ::: "memory")
#define WAITV0 asm volatile("s_waitcnt vmcnt(0)" ::: "memory")
#define SBAR   __builtin_amdgcn_s_barrier()

// -------- split: normalize + per-row i8 quantization (q = rint(127 x/max)) --
__global__ __launch_bounds__(256) void split_q_kernel(
    const float* __restrict__ base, const float* __restrict__ real,
    uchar_t* __restrict__ Ai, uchar_t* __restrict__ Bi,
    float* __restrict__ inv, float* __restrict__ sb) {
    int rid  = blockIdx.x * 4 + (threadIdx.x >> 6);
    int lane = threadIdx.x & 63;
    bool isA = rid < NB;
    int  row = isA ? rid : rid - NB;
    const float* src = isA ? base + (size_t)row * KDIM : real + (size_t)row * KDIM;
    float4 v = *(const float4*)(src + lane * 4);
    float ss = v.x * v.x + v.y * v.y + v.z * v.z + v.w * v.w;
    #pragma unroll
    for (int off = 32; off > 0; off >>= 1) ss += __shfl_xor(ss, off);
    float invn = 1.0f / fmaxf(sqrtf(ss), 1e-12f);

    float n0 = v.x * invn, n1 = v.y * invn, n2 = v.z * invn, n3 = v.w * invn;
    float am = fmaxf(fmaxf(fabsf(n0), fabsf(n1)), fmaxf(fabsf(n2), fabsf(n3)));
    #pragma unroll
    for (int off = 32; off > 0; off >>= 1) am = fmaxf(am, __shfl_xor(am, off));
    float qs = 127.0f / am;
    int q0 = (int)rintf(n0 * qs), q1 = (int)rintf(n1 * qs);
    int q2 = (int)rintf(n2 * qs), q3 = (int)rintf(n3 * qs);
    unsigned w32 = (q0 & 0xff) | ((q1 & 0xff) << 8) |
                   ((q2 & 0xff) << 16) | ((unsigned)(q3 & 0xff) << 24);
    *(unsigned*)((isA ? Ai : Bi) + (size_t)row * KDIM + lane * 4) = w32;
    if (lane == 0) {
        inv[rid] = invn;
        if (!isA) sb[row] = am / 127.0f;   // column scale for ranking keys
    }
}

// --------------------- i8 MFMA GEMM (K=256) + per-block top-4 keys ----------
// (byte-identical to the R15-passing kernel)
__global__ __launch_bounds__(256) void mfma_topk_kernel(
    const uchar_t* __restrict__ Ai, const uchar_t* __restrict__ Bi,
    const float* __restrict__ sb, unsigned* __restrict__ Pk) {
    __shared__ char sA0[8 * CHUNK];
    __shared__ char sB0[8 * CHUNK];
    __shared__ char sA1[8 * CHUNK];
    __shared__ char sB1[8 * CHUNK];

    const int tid  = threadIdx.x;
    const int lane = tid & 63;
    const int w    = tid >> 6;
    const int wr   = w >> 1, wc = w & 1;
    const int c    = lane & 15;       // frag col/row-in-16
    const int kg   = lane >> 4;       // frag k-slice (0..3), 16B each

    // ---- bijective XCD supertile remap: 8192 blocks = 8 XCD x 16 st x 8x8 --
    int lin = blockIdx.y * 64 + blockIdx.x;     // gridDim = (64, 128)
    int xcd = lin & 7;
    int pos = lin >> 3;                          // 0..1023
    int gg  = xcd * 1024 + pos;                  // chunked per-XCD range
    int st  = gg >> 6, in8 = gg & 63;            // supertile id, pos within
    int my  = ((st >> 3) << 3) + (in8 >> 3);     // 0..127 row tile
    int nx  = ((st & 7) << 3) + (in8 & 7);       // 0..63  col tile
    const int m0 = my * 128;
    const int n0 = nx * 128;

    i32x4 acc[4][4];
    #pragma unroll
    for (int i = 0; i < 4; ++i)
        #pragma unroll
        for (int j = 0; j < 4; ++j) acc[i][j] = (i32x4){0, 0, 0, 0};

    // ---- pipelined K-loop (4 gload16/wave/tile -> counted vmcnt(4)) -------
    issue_tile(Ai, Bi, m0, n0, 0,   w, lane, sA0, sB0);   // t0 -> buf0
    issue_tile(Ai, Bi, m0, n0, 64,  w, lane, sA1, sB1);   // t1 -> buf1
    WAITV4; SBAR;                         // t0 resident (t1 in flight)
    compute_tile(sA0, sB0, wr, wc, c, kg, acc);
    SBAR;                                 // all waves done reading buf0
    issue_tile(Ai, Bi, m0, n0, 128, w, lane, sA0, sB0);   // t2 -> buf0
    WAITV4; SBAR;                         // t1 resident (t2 in flight)
    compute_tile(sA1, sB1, wr, wc, c, kg, acc);
    SBAR;                                 // all waves done reading buf1
    issue_tile(Ai, Bi, m0, n0, 192, w, lane, sA1, sB1);   // t3 -> buf1
    WAITV4; SBAR;                         // t2 resident (t3 in flight)
    compute_tile(sA0, sB0, wr, wc, c, kg, acc);
    WAITV0; SBAR;                         // t3 resident
    compute_tile(sA1, sB1, wr, wc, c, kg, acc);

    // ---- epilogue: column scales (outside counted region) ------------------
    float sbj[4];
    #pragma unroll
    for (int j = 0; j < 4; ++j) sbj[j] = sb[n0 + wc * 64 + j * 16 + c];

    // ---- per-row top-4 keys over this block's 128 cols ----
    __syncthreads();                       // full drain; reuse LDS below
    unsigned* mk = (unsigned*)sA0;         // [128][2][4] keys (4KB)
    #pragma unroll
    for (int i = 0; i < 4; ++i) {
        #pragma unroll
        for (int r = 0; r < 4; ++r) {
            unsigned k0 = ((__float_as_uint((float)acc[i][0][r] * sbj[0] + 8192.0f)
                            - 0x45B00000u) << 7) | (unsigned)(wc * 64 + 0 * 16 + c);
            unsigned k1 = ((__float_as_uint((float)acc[i][1][r] * sbj[1] + 8192.0f)
                            - 0x45B00000u) << 7) | (unsigned)(wc * 64 + 1 * 16 + c);
            unsigned k2 = ((__float_as_uint((float)acc[i][2][r] * sbj[2] + 8192.0f)
                            - 0x45B00000u) << 7) | (unsigned)(wc * 64 + 2 * 16 + c);
            unsigned k3 = ((__float_as_uint((float)acc[i][3][r] * sbj[3] + 8192.0f)
                            - 0x45B00000u) << 7) | (unsigned)(wc * 64 + 3 * 16 + c);
            unsigned top[4];
            #pragma unroll
            for (int p = 0; p < 4; ++p) {
                unsigned m01 = k0 > k1 ? k0 : k1;
                unsigned m23 = k2 > k3 ? k2 : k3;
                unsigned m   = m01 > m23 ? m01 : m23;
                m = rowmax16(m);           // VALU DPP, no DS ops
                top[p] = m;
                k0 = (k0 == m) ? 0u : k0;
                k1 = (k1 == m) ? 0u : k1;
                k2 = (k2 == m) ? 0u : k2;
                k3 = (k3 == m) ? 0u : k3;
            }
            if (c == 0) {
                int row = wr * 64 + i * 16 + kg * 4 + r;
                *(uint4*)&mk[(row * 2 + wc) * 4] =
                    make_uint4(top[0], top[1], top[2], top[3]);
            }
        }
    }
    __syncthreads();
    if (tid < 128) {
        unsigned e[8];
        *(uint4*)&e[0] = *(const uint4*)&mk[tid * 8];
        *(uint4*)&e[4] = *(const uint4*)&mk[tid * 8 + 4];
        unsigned top[4];
        #pragma unroll
        for (int p = 0; p < 4; ++p) {
            unsigned m = e[0];
            #pragma unroll
            for (int q = 1; q < 8; ++q) m = e[q] > m ? e[q] : m;
            top[p] = m;
            #pragma unroll
            for (int q = 0; q < 8; ++q) e[q] = (e[q] == m) ? 0u : e[q];
        }
        size_t o = (size_t)(m0 + tid) * 256 + nx * 4;   // [row][64 blocks][4]
        *(uint4*)&Pk[o] = make_uint4(top[0], top[1], top[2], top[3]);
    }
}

// ---- stage-2: u32-ekey butterfly -> global top-8 (R15-proven margin), then
// consolidated exact f32 rerank: wave 0 reranks 4 rows x 8 cands on 32 lanes.
// Same candidates, same fmaf chain/order, same ins3 sequence as R15's merge8
// -> bit-identical outputs; only the issuing wave changes (4x less issue).
__global__ __launch_bounds__(256) void merge8c_kernel(
    const unsigned* __restrict__ Pk,
    const float* __restrict__ base, const float* __restrict__ real,
    const float* __restrict__ inv, int* __restrict__ out) {
    const int tid  = threadIdx.x;
    const int w    = tid >> 6;
    const int lane = tid & 63;
    int row  = blockIdx.x * 4 + w;
    uint4 kv = *(const uint4*)(Pk + (size_t)row * 256 + lane * 4);

    unsigned k[4];
    {
        unsigned kk[4] = {kv.x, kv.y, kv.z, kv.w};
        #pragma unroll
        for (int e = 0; e < 4; ++e) {
            int idx = lane * 128 + (int)(kk[e] & 127u);
            k[e] = ((kk[e] >> 12) << 13) | (unsigned)(8191 - idx);
        }
    }

    __shared__ int cl[4][8];
    #pragma unroll
    for (int p = 0; p < 8; ++p) {
        unsigned m01 = k[0] > k[1] ? k[0] : k[1];
        unsigned m23 = k[2] > k[3] ? k[2] : k[3];
        unsigned m   = m01 > m23 ? m01 : m23;
        #pragma unroll
        for (int mask = 1; mask <= 32; mask <<= 1) {
            unsigned om = (unsigned)__shfl_xor((int)m, mask);
            m = om > m ? om : m;
        }
        if (lane == 0) cl[w][p] = 8191 - (int)(m & 8191u);
        #pragma unroll
        for (int e = 0; e < 4; ++e) k[e] = (k[e] == m) ? 0u : k[e];
    }
    __syncthreads();

    if (w == 0) {
        int rloc = (lane >> 3) & 3;          // row slot 0..3
        int cd   = cl[rloc][lane & 7];       // candidate for this lane
        int r    = blockIdx.x * 4 + rloc;
        float s  = 0.0f;
        if (lane < 32) {
            const float* a = base + (size_t)r  * KDIM;
            const float* b = real + (size_t)cd * KDIM;
            float ia = inv[r], ib = inv[NB + cd];
            #pragma unroll 4
            for (int kq = 0; kq < KDIM; kq += 4) {
                float4 av = *(const float4*)(a + kq);
                float4 bv = *(const float4*)(b + kq);
                s = fmaf(av.x * ia, bv.x * ib, s);
                s = fmaf(av.y * ia, bv.y * ib, s);
                s = fmaf(av.z * ia, bv.z * ib, s);
                s = fmaf(av.w * ia, bv.w * ib, s);
            }
        }
        // top-3 within each 8-lane group (one group per row), cnd order l=0..7
        float fv0 = -3.0e38f, fv1 = -3.0e38f, fv2 = -3.0e38f;
        int   fi0 = 0x7fffffff, fi1 = 0x7fffffff, fi2 = 0x7fffffff;
        int bl = lane & ~7;                  // group base lane
        #pragma unroll
        for (int l = 0; l < 8; ++l) {
            float sv = __shfl(s, bl + l);
            int   si = __shfl(cd, bl + l);
            ins3(sv, si, fv0, fi0, fv1, fi1, fv2, fi2);
        }
        if (lane < 32 && (lane & 7) == 0) {
            out[r * 3 + 0] = fi0;
            out[r * 3 + 1] = fi1;
            out[r * 3 + 2] = fi2;
        }
    }
}

// ======================= fallback (round-1 f32 path) ========================
__global__ __launch_bounds__(256) void norm_kernel(const float* __restrict__ base,
                                                   const float* __restrict__ real,
                                                   float* __restrict__ inv) {
    int rid  = blockIdx.x * 4 + (threadIdx.x >> 6);
    int lane = threadIdx.x & 63;
    if (rid >= NB + NR) return;
    const float* src = (rid < NB) ? (base + (size_t)rid * KDIM)
                                  : (real + (size_t)(rid - NB) * KDIM);
    float4 v = *(const float4*)(src + lane * 4);
    float ss = v.x * v.x + v.y * v.y + v.z * v.z + v.w * v.w;
    #pragma unroll
    for (int off = 32; off > 0; off >>= 1) ss += __shfl_xor(ss, off);
    if (lane == 0) inv[rid] = 1.0f / fmaxf(sqrtf(ss), 1e-12f);
}

#define DOT(i, j, av, bv)                                                      \
    acc[i][j] = fmaf(av.x, bv.x, acc[i][j]);                                   \
    acc[i][j] = fmaf(av.y, bv.y, acc[i][j]);                                   \
    acc[i][j] = fmaf(av.z, bv.z, acc[i][j]);                                   \
    acc[i][j] = fmaf(av.w, bv.w, acc[i][j]);

__global__ __launch_bounds__(256) void simtopk_kernel(
    const float* __restrict__ A, const float* __restrict__ B,
    const float* __restrict__ invA, const float* __restrict__ invB,
    int* __restrict__ out) {
    __shared__ float sA[64 * 68];
    __shared__ float sB[64 * 68];
    const int tid = threadIdx.x;
    const int tx  = tid & 15;
    const int ty4 = (tid >> 4) << 2;
    const int m0  = blockIdx.x * 64;
    float t3v[4][3];
    int   t3i[4][3];
    #pragma unroll
    for (int i = 0; i < 4; ++i)
        #pragma unroll
        for (int s = 0; s < 3; ++s) { t3v[i][s] = -3.0e38f; t3i[i][s] = 0x7fffffff; }
    for (int nn0 = 0; nn0 < NR; nn0 += 64) {
        float acc[4][4] = {{0.f}};
        for (int kc = 0; kc < KDIM; kc += 64) {
            __syncthreads();
            #pragma unroll
            for (int p = 0; p < 4; ++p) {
                int f = tid + (p << 8), row = f >> 4, c4 = (f & 15) << 2;
                float4 va = *(const float4*)(A + (size_t)(m0 + row) * KDIM + kc + c4);
                float  sa = invA[m0 + row];
                va.x *= sa; va.y *= sa; va.z *= sa; va.w *= sa;
                *(float4*)&sA[row * 68 + c4] = va;
                float4 vb = *(const float4*)(B + (size_t)(nn0 + row) * KDIM + kc + c4);
                float  sb2 = invB[nn0 + row];
                vb.x *= sb2; vb.y *= sb2; vb.z *= sb2; vb.w *= sb2;
                *(float4*)&sB[row * 68 + c4] = vb;
            }
            __syncthreads();
            #pragma unroll
            for (int k = 0; k < 64; k += 4) {
                float4 a0 = *(const float4*)&sA[(ty4 + 0) * 68 + k];
                float4 a1 = *(const float4*)&sA[(ty4 + 1) * 68 + k];
                float4 a2 = *(const float4*)&sA[(ty4 + 2) * 68 + k];
                float4 a3 = *(const float4*)&sA[(ty4 + 3) * 68 + k];
                float4 b0 = *(const float4*)&sB[(tx +  0) * 68 + k];
                float4 b1 = *(const float4*)&sB[(tx + 16) * 68 + k];
                float4 b2 = *(const float4*)&sB[(tx + 32) * 68 + k];
                float4 b3 = *(const float4*)&sB[(tx + 48) * 68 + k];
                DOT(0,0,a0,b0) DOT(0,1,a0,b1) DOT(0,2,a0,b2) DOT(0,3,a0,b3)
                DOT(1,0,a1,b0) DOT(1,1,a1,b1) DOT(1,2,a1,b2) DOT(1,3,a1,b3)
                DOT(2,0,a2,b0) DOT(2,1,a2,b1) DOT(2,2,a2,b2) DOT(2,3,a2,b3)
                DOT(3,0,a3,b0) DOT(3,1,a3,b1) DOT(3,2,a3,b2) DOT(3,3,a3,b3)
            }
        }
        #pragma unroll
        for (int i = 0; i < 4; ++i)
            #pragma unroll
            for (int j = 0; j < 4; ++j)
                ins3f(acc[i][j], nn0 + tx + 16 * j, t3v[i], t3i[i]);
    }
    __syncthreads();
    float* mv = sA;
    int*   mi = (int*)sB;
    #pragma unroll
    for (int i = 0; i < 4; ++i)
        #pragma unroll
        for (int s = 0; s < 3; ++s) {
            mv[(ty4 + i) * 48 + tx * 3 + s] = t3v[i][s];
            mi[(ty4 + i) * 48 + tx * 3 + s] = t3i[i][s];
        }
    __syncthreads();
    if (tid < 64) {
        float v0 = -3.0e38f, v1 = -3.0e38f, v2 = -3.0e38f;
        int   i0 = 0x7fffffff, i1 = 0x7fffffff, i2 = 0x7fffffff;
        for (int e = 0; e < 48; ++e)
            ins3(mv[tid * 48 + e], mi[tid * 48 + e], v0, i0, v1, i1, v2, i2);
        out[(m0 + tid) * 3 + 0] = i0;
        out[(m0 + tid) * 3 + 1] = i1;
        out[(m0 + tid) * 3 + 2] = i2;
    }
}

// ============================================================== launcher ====
extern "C" void kernel_launch(void* const* d_in, const int* in_sizes, int n_in,
                              void* d_out, int out_size, void* d_ws, size_t ws_size,
                              hipStream_t stream) {
    const float* base = (const float*)d_in[0];
    const float* real = (const float*)d_in[1];
    int* out = (int*)d_out;

    const size_t szAi  = (size_t)NB * KDIM;          // 4.2 MB (i8)
    const size_t szBi  = (size_t)NR * KDIM;          // 2.1 MB (i8)
    const size_t szPk  = (size_t)NB * 256 * 4;       // 16.8 MB
    const size_t szInv = (size_t)(NB + NR) * 4;      // 0.1 MB
    const size_t szSb  = (size_t)NR * 4;             // 0.03 MB
    const size_t need  = szAi + szBi + szPk + szInv + szSb;

    if (ws_size >= need) {
        char* p = (char*)d_ws;
        uchar_t*  Ai  = (uchar_t*)(p);
        uchar_t*  Bi  = (uchar_t*)(p + szAi);
        unsigned* Pk  = (unsigned*)(p + szAi + szBi);
        float*    inv = (float*)   (p + szAi + szBi + szPk);
        float*    sb  = (float*)   (p + szAi + szBi + szPk + szInv);

        hipLaunchKernelGGL(split_q_kernel, dim3((NB + NR) / 4), dim3(256), 0, stream,
                           base, real, Ai, Bi, inv, sb);
        hipLaunchKernelGGL(mfma_topk_kernel, dim3(NR / 128, NB / 128), dim3(256), 0,
                           stream, Ai, Bi, sb, Pk);
        hipLaunchKernelGGL(merge8c_kernel, dim3(NB / 4), dim3(256), 0, stream,
                           Pk, base, real, inv, out);
    } else {
        float* inv = (float*)d_ws;
        hipLaunchKernelGGL(norm_kernel, dim3((NB + NR) / 4), dim3(256), 0, stream,
                           base, real, inv);
        hipLaunchKernelGGL(simtopk_kernel, dim3(NB / 64), dim3(256), 0, stream,
                           base, real, inv, inv + NB, out);
    }
}

// Round 18
// 112.111 us; speedup vs baseline: 2.0741x; 1.0930x over previous
//
#include <hip/hip_runtime.h>

#define KDIM 256
#define NB 16384
#define NR 8192
#define CHUNK 1088            // 1024B data (16 rows x 64B i8) + 64B pad

typedef unsigned short ushort_t;
typedef unsigned char uchar_t;
typedef __attribute__((ext_vector_type(4))) int i32x4;

// ---------------------------------------------------------------- helpers ---
__device__ __forceinline__ void gload16(const void* g, void* l) {
    __builtin_amdgcn_global_load_lds(
        (const __attribute__((address_space(1))) void*)g,
        (__attribute__((address_space(3))) void*)l, 16, 0, 0);
}
// 16-lane all-reduce max on the VALU pipe: v_max through DPP row rotations
__device__ __forceinline__ unsigned rowmax16(unsigned m) {
    unsigned t;
    t = (unsigned)__builtin_amdgcn_update_dpp(0, (int)m, 0x121, 0xf, 0xf, true);
    m = t > m ? t : m;
    t = (unsigned)__builtin_amdgcn_update_dpp(0, (int)m, 0x122, 0xf, 0xf, true);
    m = t > m ? t : m;
    t = (unsigned)__builtin_amdgcn_update_dpp(0, (int)m, 0x124, 0xf, 0xf, true);
    m = t > m ? t : m;
    t = (unsigned)__builtin_amdgcn_update_dpp(0, (int)m, 0x128, 0xf, 0xf, true);
    m = t > m ? t : m;
    return m;
}
// branchless insert into sorted top-3 (v desc, idx asc on ties)
__device__ __forceinline__ void ins3(float v, int idx,
                                     float& v0, int& i0, float& v1, int& i1,
                                     float& v2, int& i2) {
    bool b0 = (v > v0) | ((v == v0) & (idx < i0));
    bool b1 = (v > v1) | ((v == v1) & (idx < i1));
    bool b2 = (v > v2) | ((v == v2) & (idx < i2));
    float nv2 = b1 ? v1 : (b2 ? v : v2);
    int   ni2 = b1 ? i1 : (b2 ? idx : i2);
    float nv1 = b0 ? v0 : (b1 ? v : v1);
    int   ni1 = b0 ? i0 : (b1 ? idx : i1);
    float nv0 = b0 ? v : v0;
    int   ni0 = b0 ? idx : i0;
    v0 = nv0; i0 = ni0; v1 = nv1; i1 = ni1; v2 = nv2; i2 = ni2;
}
__device__ __forceinline__ void ins3f(float v, int idx, float* tv, int* ti) {
    ins3(v, idx, tv[0], ti[0], tv[1], ti[1], tv[2], ti[2]);
}
// compare-exchange for descending sort
#define CEX(a, b) { unsigned h_ = (a) > (b) ? (a) : (b);                       \
                    unsigned l_ = (a) > (b) ? (b) : (a); (a) = h_; (b) = l_; }

// i8 GEMM tile helpers. Staging: chunk = 16 rows x 64B; source slice index
// s = p ^ ((row>>1)&3) (permutes WITHIN one 64B row -> coalescing kept);
// frag reads then hit banks 16(c&1)+4(g^((c>>1)&3)) -> all 32 banks, 2-way.
__device__ __forceinline__ void issue_tile(
    const uchar_t* __restrict__ Ai, const uchar_t* __restrict__ Bi,
    int m0, int n0, int kc, int w, int lane, char* dA, char* dB) {
    int lr  = lane >> 2;                       // row within 16-row chunk
    int sl  = (lane & 3) ^ ((lane >> 3) & 3);  // pre-swizzled source slice
    #pragma unroll
    for (int q = 0; q < 2; ++q) {
        int cq = w * 2 + q;                    // chunk id 0..7
        gload16(Ai + (size_t)(m0 + cq * 16 + lr) * KDIM + kc + sl * 16,
                dA + cq * CHUNK);
        gload16(Bi + (size_t)(n0 + cq * 16 + lr) * KDIM + kc + sl * 16,
                dB + cq * CHUNK);
    }
}
__device__ __forceinline__ void compute_tile(
    const char* rA, const char* rB, int wr, int wc, int c, int kg,
    i32x4 (*acc)[4]) {
    i32x4 a[4], b[4];
    #pragma unroll
    for (int i = 0; i < 4; ++i) {
        int ra = wr * 64 + i * 16 + c;
        a[i] = *(const i32x4*)(rA + (ra >> 4) * CHUNK + (ra & 15) * 64 +
                               ((kg ^ ((ra >> 1) & 3)) << 4));
        int rb = wc * 64 + i * 16 + c;
        b[i] = *(const i32x4*)(rB + (rb >> 4) * CHUNK + (rb & 15) * 64 +
                               ((kg ^ ((rb >> 1) & 3)) << 4));
    }
    #pragma unroll
    for (int i = 0; i < 4; ++i)
        #pragma unroll
        for (int j = 0; j < 4; ++j)
            acc[i][j] = __builtin_amdgcn_mfma_i32_16x16x64_i8(
                a[i], b[j], acc[i][j], 0, 0, 0);
}

#define WAITV4 asm volatile("s_waitcnt vmcnt(4)" ::: "memory")
#define WAITV0 asm volatile("s_waitcnt vmcnt(0)" ::: "memory")
#define SBAR   __builtin_amdgcn_s_barrier()

// -------- split: normalize + per-row i8 quantization (q = rint(127 x/max)) --
__global__ __launch_bounds__(256) void split_q_kernel(
    const float* __restrict__ base, const float* __restrict__ real,
    uchar_t* __restrict__ Ai, uchar_t* __restrict__ Bi,
    float* __restrict__ inv, float* __restrict__ sb) {
    int rid  = blockIdx.x * 4 + (threadIdx.x >> 6);
    int lane = threadIdx.x & 63;
    bool isA = rid < NB;
    int  row = isA ? rid : rid - NB;
    const float* src = isA ? base + (size_t)row * KDIM : real + (size_t)row * KDIM;
    float4 v = *(const float4*)(src + lane * 4);
    float ss = v.x * v.x + v.y * v.y + v.z * v.z + v.w * v.w;
    #pragma unroll
    for (int off = 32; off > 0; off >>= 1) ss += __shfl_xor(ss, off);
    float invn = 1.0f / fmaxf(sqrtf(ss), 1e-12f);

    float n0 = v.x * invn, n1 = v.y * invn, n2 = v.z * invn, n3 = v.w * invn;
    float am = fmaxf(fmaxf(fabsf(n0), fabsf(n1)), fmaxf(fabsf(n2), fabsf(n3)));
    #pragma unroll
    for (int off = 32; off > 0; off >>= 1) am = fmaxf(am, __shfl_xor(am, off));
    float qs = 127.0f / am;
    int q0 = (int)rintf(n0 * qs), q1 = (int)rintf(n1 * qs);
    int q2 = (int)rintf(n2 * qs), q3 = (int)rintf(n3 * qs);
    unsigned w32 = (q0 & 0xff) | ((q1 & 0xff) << 8) |
                   ((q2 & 0xff) << 16) | ((unsigned)(q3 & 0xff) << 24);
    *(unsigned*)((isA ? Ai : Bi) + (size_t)row * KDIM + lane * 4) = w32;
    if (lane == 0) {
        inv[rid] = invn;
        if (!isA) sb[row] = am / 127.0f;   // column scale for ranking keys
    }
}

// --------------------- i8 MFMA GEMM (K=256) + per-block top-4 keys ----------
// GEMM pipeline byte-identical to R15/R17. Extraction: sorted-shift
// (sort4 desc once; per pass = DPP max of s0 + unique-owner register shift)
// -- provably same top-4/order as the clear-based extractor (keys unique
// via col bits), ~220 fewer VALU instrs/thread.
__global__ __launch_bounds__(256) void mfma_topk_kernel(
    const uchar_t* __restrict__ Ai, const uchar_t* __restrict__ Bi,
    const float* __restrict__ sb, unsigned* __restrict__ Pk) {
    __shared__ char sA0[8 * CHUNK];
    __shared__ char sB0[8 * CHUNK];
    __shared__ char sA1[8 * CHUNK];
    __shared__ char sB1[8 * CHUNK];

    const int tid  = threadIdx.x;
    const int lane = tid & 63;
    const int w    = tid >> 6;
    const int wr   = w >> 1, wc = w & 1;
    const int c    = lane & 15;       // frag col/row-in-16
    const int kg   = lane >> 4;       // frag k-slice (0..3), 16B each

    // ---- bijective XCD supertile remap: 8192 blocks = 8 XCD x 16 st x 8x8 --
    int lin = blockIdx.y * 64 + blockIdx.x;     // gridDim = (64, 128)
    int xcd = lin & 7;
    int pos = lin >> 3;                          // 0..1023
    int gg  = xcd * 1024 + pos;                  // chunked per-XCD range
    int st  = gg >> 6, in8 = gg & 63;            // supertile id, pos within
    int my  = ((st >> 3) << 3) + (in8 >> 3);     // 0..127 row tile
    int nx  = ((st & 7) << 3) + (in8 & 7);       // 0..63  col tile
    const int m0 = my * 128;
    const int n0 = nx * 128;

    i32x4 acc[4][4];
    #pragma unroll
    for (int i = 0; i < 4; ++i)
        #pragma unroll
        for (int j = 0; j < 4; ++j) acc[i][j] = (i32x4){0, 0, 0, 0};

    // ---- pipelined K-loop (4 gload16/wave/tile -> counted vmcnt(4)) -------
    issue_tile(Ai, Bi, m0, n0, 0,   w, lane, sA0, sB0);   // t0 -> buf0
    issue_tile(Ai, Bi, m0, n0, 64,  w, lane, sA1, sB1);   // t1 -> buf1
    WAITV4; SBAR;                         // t0 resident (t1 in flight)
    compute_tile(sA0, sB0, wr, wc, c, kg, acc);
    SBAR;                                 // all waves done reading buf0
    issue_tile(Ai, Bi, m0, n0, 128, w, lane, sA0, sB0);   // t2 -> buf0
    WAITV4; SBAR;                         // t1 resident (t2 in flight)
    compute_tile(sA1, sB1, wr, wc, c, kg, acc);
    SBAR;                                 // all waves done reading buf1
    issue_tile(Ai, Bi, m0, n0, 192, w, lane, sA1, sB1);   // t3 -> buf1
    WAITV4; SBAR;                         // t2 resident (t3 in flight)
    compute_tile(sA0, sB0, wr, wc, c, kg, acc);
    WAITV0; SBAR;                         // t3 resident
    compute_tile(sA1, sB1, wr, wc, c, kg, acc);

    // ---- epilogue: column scales (outside counted region) ------------------
    float sbj[4];
    #pragma unroll
    for (int j = 0; j < 4; ++j) sbj[j] = sb[n0 + wc * 64 + j * 16 + c];

    // ---- per-row top-4 keys over this block's 128 cols (sorted-shift) ----
    __syncthreads();                       // full drain; reuse LDS below
    unsigned* mk = (unsigned*)sA0;         // [128][2][4] keys (4KB)
    #pragma unroll
    for (int i = 0; i < 4; ++i) {
        #pragma unroll
        for (int r = 0; r < 4; ++r) {
            unsigned s0 = ((__float_as_uint((float)acc[i][0][r] * sbj[0] + 8192.0f)
                            - 0x45B00000u) << 7) | (unsigned)(wc * 64 + 0 * 16 + c);
            unsigned s1 = ((__float_as_uint((float)acc[i][1][r] * sbj[1] + 8192.0f)
                            - 0x45B00000u) << 7) | (unsigned)(wc * 64 + 1 * 16 + c);
            unsigned s2 = ((__float_as_uint((float)acc[i][2][r] * sbj[2] + 8192.0f)
                            - 0x45B00000u) << 7) | (unsigned)(wc * 64 + 2 * 16 + c);
            unsigned s3 = ((__float_as_uint((float)acc[i][3][r] * sbj[3] + 8192.0f)
                            - 0x45B00000u) << 7) | (unsigned)(wc * 64 + 3 * 16 + c);
            CEX(s0, s1) CEX(s2, s3) CEX(s0, s2) CEX(s1, s3) CEX(s1, s2)
            unsigned top[4];
            #pragma unroll
            for (int p = 0; p < 4; ++p) {
                unsigned m = rowmax16(s0);     // VALU DPP, no DS ops
                top[p] = m;
                bool own = (s0 == m);          // unique owner (col bits)
                s0 = own ? s1 : s0;
                s1 = own ? s2 : s1;
                s2 = own ? s3 : s2;
                s3 = own ? 0u : s3;
            }
            if (c == 0) {
                int row = wr * 64 + i * 16 + kg * 4 + r;
                *(uint4*)&mk[(row * 2 + wc) * 4] =
                    make_uint4(top[0], top[1], top[2], top[3]);
            }
        }
    }
    __syncthreads();
    if (tid < 128) {
        unsigned e[8];
        *(uint4*)&e[0] = *(const uint4*)&mk[tid * 8];
        *(uint4*)&e[4] = *(const uint4*)&mk[tid * 8 + 4];
        unsigned top[4];
        #pragma unroll
        for (int p = 0; p < 4; ++p) {
            unsigned m = e[0];
            #pragma unroll
            for (int q = 1; q < 8; ++q) m = e[q] > m ? e[q] : m;
            top[p] = m;
            #pragma unroll
            for (int q = 0; q < 8; ++q) e[q] = (e[q] == m) ? 0u : e[q];
        }
        size_t o = (size_t)(m0 + tid) * 256 + nx * 4;   // [row][64 blocks][4]
        *(uint4*)&Pk[o] = make_uint4(top[0], top[1], top[2], top[3]);
    }
}

// ---- stage-2: u32-ekey butterfly -> global top-8 (R15-proven margin), then
// consolidated exact f32 rerank: wave 0 reranks 4 rows x 8 cands on 32 lanes.
// (byte-identical to the R17-passing kernel)
__global__ __launch_bounds__(256) void merge8c_kernel(
    const unsigned* __restrict__ Pk,
    const float* __restrict__ base, const float* __restrict__ real,
    const float* __restrict__ inv, int* __restrict__ out) {
    const int tid  = threadIdx.x;
    const int w    = tid >> 6;
    const int lane = tid & 63;
    int row  = blockIdx.x * 4 + w;
    uint4 kv = *(const uint4*)(Pk + (size_t)row * 256 + lane * 4);

    unsigned k[4];
    {
        unsigned kk[4] = {kv.x, kv.y, kv.z, kv.w};
        #pragma unroll
        for (int e = 0; e < 4; ++e) {
            int idx = lane * 128 + (int)(kk[e] & 127u);
            k[e] = ((kk[e] >> 12) << 13) | (unsigned)(8191 - idx);
        }
    }

    __shared__ int cl[4][8];
    #pragma unroll
    for (int p = 0; p < 8; ++p) {
        unsigned m01 = k[0] > k[1] ? k[0] : k[1];
        unsigned m23 = k[2] > k[3] ? k[2] : k[3];
        unsigned m   = m01 > m23 ? m01 : m23;
        #pragma unroll
        for (int mask = 1; mask <= 32; mask <<= 1) {
            unsigned om = (unsigned)__shfl_xor((int)m, mask);
            m = om > m ? om : m;
        }
        if (lane == 0) cl[w][p] = 8191 - (int)(m & 8191u);
        #pragma unroll
        for (int e = 0; e < 4; ++e) k[e] = (k[e] == m) ? 0u : k[e];
    }
    __syncthreads();

    if (w == 0) {
        int rloc = (lane >> 3) & 3;          // row slot 0..3
        int cd   = cl[rloc][lane & 7];       // candidate for this lane
        int r    = blockIdx.x * 4 + rloc;
        float s  = 0.0f;
        if (lane < 32) {
            const float* a = base + (size_t)r  * KDIM;
            const float* b = real + (size_t)cd * KDIM;
            float ia = inv[r], ib = inv[NB + cd];
            #pragma unroll 4
            for (int kq = 0; kq < KDIM; kq += 4) {
                float4 av = *(const float4*)(a + kq);
                float4 bv = *(const float4*)(b + kq);
                s = fmaf(av.x * ia, bv.x * ib, s);
                s = fmaf(av.y * ia, bv.y * ib, s);
                s = fmaf(av.z * ia, bv.z * ib, s);
                s = fmaf(av.w * ia, bv.w * ib, s);
            }
        }
        // top-3 within each 8-lane group (one group per row), cnd order l=0..7
        float fv0 = -3.0e38f, fv1 = -3.0e38f, fv2 = -3.0e38f;
        int   fi0 = 0x7fffffff, fi1 = 0x7fffffff, fi2 = 0x7fffffff;
        int bl = lane & ~7;                  // group base lane
        #pragma unroll
        for (int l = 0; l < 8; ++l) {
            float sv = __shfl(s, bl + l);
            int   si = __shfl(cd, bl + l);
            ins3(sv, si, fv0, fi0, fv1, fi1, fv2, fi2);
        }
        if (lane < 32 && (lane & 7) == 0) {
            out[r * 3 + 0] = fi0;
            out[r * 3 + 1] = fi1;
            out[r * 3 + 2] = fi2;
        }
    }
}

// ======================= fallback (round-1 f32 path) ========================
__global__ __launch_bounds__(256) void norm_kernel(const float* __restrict__ base,
                                                   const float* __restrict__ real,
                                                   float* __restrict__ inv) {
    int rid  = blockIdx.x * 4 + (threadIdx.x >> 6);
    int lane = threadIdx.x & 63;
    if (rid >= NB + NR) return;
    const float* src = (rid < NB) ? (base + (size_t)rid * KDIM)
                                  : (real + (size_t)(rid - NB) * KDIM);
    float4 v = *(const float4*)(src + lane * 4);
    float ss = v.x * v.x + v.y * v.y + v.z * v.z + v.w * v.w;
    #pragma unroll
    for (int off = 32; off > 0; off >>= 1) ss += __shfl_xor(ss, off);
    if (lane == 0) inv[rid] = 1.0f / fmaxf(sqrtf(ss), 1e-12f);
}

#define DOT(i, j, av, bv)                                                      \
    acc[i][j] = fmaf(av.x, bv.x, acc[i][j]);                                   \
    acc[i][j] = fmaf(av.y, bv.y, acc[i][j]);                                   \
    acc[i][j] = fmaf(av.z, bv.z, acc[i][j]);                                   \
    acc[i][j] = fmaf(av.w, bv.w, acc[i][j]);

__global__ __launch_bounds__(256) void simtopk_kernel(
    const float* __restrict__ A, const float* __restrict__ B,
    const float* __restrict__ invA, const float* __restrict__ invB,
    int* __restrict__ out) {
    __shared__ float sA[64 * 68];
    __shared__ float sB[64 * 68];
    const int tid = threadIdx.x;
    const int tx  = tid & 15;
    const int ty4 = (tid >> 4) << 2;
    const int m0  = blockIdx.x * 64;
    float t3v[4][3];
    int   t3i[4][3];
    #pragma unroll
    for (int i = 0; i < 4; ++i)
        #pragma unroll
        for (int s = 0; s < 3; ++s) { t3v[i][s] = -3.0e38f; t3i[i][s] = 0x7fffffff; }
    for (int nn0 = 0; nn0 < NR; nn0 += 64) {
        float acc[4][4] = {{0.f}};
        for (int kc = 0; kc < KDIM; kc += 64) {
            __syncthreads();
            #pragma unroll
            for (int p = 0; p < 4; ++p) {
                int f = tid + (p << 8), row = f >> 4, c4 = (f & 15) << 2;
                float4 va = *(const float4*)(A + (size_t)(m0 + row) * KDIM + kc + c4);
                float  sa = invA[m0 + row];
                va.x *= sa; va.y *= sa; va.z *= sa; va.w *= sa;
                *(float4*)&sA[row * 68 + c4] = va;
                float4 vb = *(const float4*)(B + (size_t)(nn0 + row) * KDIM + kc + c4);
                float  sb2 = invB[nn0 + row];
                vb.x *= sb2; vb.y *= sb2; vb.z *= sb2; vb.w *= sb2;
                *(float4*)&sB[row * 68 + c4] = vb;
            }
            __syncthreads();
            #pragma unroll
            for (int k = 0; k < 64; k += 4) {
                float4 a0 = *(const float4*)&sA[(ty4 + 0) * 68 + k];
                float4 a1 = *(const float4*)&sA[(ty4 + 1) * 68 + k];
                float4 a2 = *(const float4*)&sA[(ty4 + 2) * 68 + k];
                float4 a3 = *(const float4*)&sA[(ty4 + 3) * 68 + k];
                float4 b0 = *(const float4*)&sB[(tx +  0) * 68 + k];
                float4 b1 = *(const float4*)&sB[(tx + 16) * 68 + k];
                float4 b2 = *(const float4*)&sB[(tx + 32) * 68 + k];
                float4 b3 = *(const float4*)&sB[(tx + 48) * 68 + k];
                DOT(0,0,a0,b0) DOT(0,1,a0,b1) DOT(0,2,a0,b2) DOT(0,3,a0,b3)
                DOT(1,0,a1,b0) DOT(1,1,a1,b1) DOT(1,2,a1,b2) DOT(1,3,a1,b3)
                DOT(2,0,a2,b0) DOT(2,1,a2,b1) DOT(2,2,a2,b2) DOT(2,3,a2,b3)
                DOT(3,0,a3,b0) DOT(3,1,a3,b1) DOT(3,2,a3,b2) DOT(3,3,a3,b3)
            }
        }
        #pragma unroll
        for (int i = 0; i < 4; ++i)
            #pragma unroll
            for (int j = 0; j < 4; ++j)
                ins3f(acc[i][j], nn0 + tx + 16 * j, t3v[i], t3i[i]);
    }
    __syncthreads();
    float* mv = sA;
    int*   mi = (int*)sB;
    #pragma unroll
    for (int i = 0; i < 4; ++i)
        #pragma unroll
        for (int s = 0; s < 3; ++s) {
            mv[(ty4 + i) * 48 + tx * 3 + s] = t3v[i][s];
            mi[(ty4 + i) * 48 + tx * 3 + s] = t3i[i][s];
        }
    __syncthreads();
    if (tid < 64) {
        float v0 = -3.0e38f, v1 = -3.0e38f, v2 = -3.0e38f;
        int   i0 = 0x7fffffff, i1 = 0x7fffffff, i2 = 0x7fffffff;
        for (int e = 0; e < 48; ++e)
            ins3(mv[tid * 48 + e], mi[tid * 48 + e], v0, i0, v1, i1, v2, i2);
        out[(m0 + tid) * 3 + 0] = i0;
        out[(m0 + tid) * 3 + 1] = i1;
        out[(m0 + tid) * 3 + 2] = i2;
    }
}

// ============================================================== launcher ====
extern "C" void kernel_launch(void* const* d_in, const int* in_sizes, int n_in,
                              void* d_out, int out_size, void* d_ws, size_t ws_size,
                              hipStream_t stream) {
    const float* base = (const float*)d_in[0];
    const float* real = (const float*)d_in[1];
    int* out = (int*)d_out;

    const size_t szAi  = (size_t)NB * KDIM;          // 4.2 MB (i8)
    const size_t szBi  = (size_t)NR * KDIM;          // 2.1 MB (i8)
    const size_t szPk  = (size_t)NB * 256 * 4;       // 16.8 MB
    const size_t szInv = (size_t)(NB + NR) * 4;      // 0.1 MB
    const size_t szSb  = (size_t)NR * 4;             // 0.03 MB
    const size_t need  = szAi + szBi + szPk + szInv + szSb;

    if (ws_size >= need) {
        char* p = (char*)d_ws;
        uchar_t*  Ai  = (uchar_t*)(p);
        uchar_t*  Bi  = (uchar_t*)(p + szAi);
        unsigned* Pk  = (unsigned*)(p + szAi + szBi);
        float*    inv = (float*)   (p + szAi + szBi + szPk);
        float*    sb  = (float*)   (p + szAi + szBi + szPk + szInv);

        hipLaunchKernelGGL(split_q_kernel, dim3((NB + NR) / 4), dim3(256), 0, stream,
                           base, real, Ai, Bi, inv, sb);
        hipLaunchKernelGGL(mfma_topk_kernel, dim3(NR / 128, NB / 128), dim3(256), 0,
                           stream, Ai, Bi, sb, Pk);
        hipLaunchKernelGGL(merge8c_kernel, dim3(NB / 4), dim3(256), 0, stream,
                           Pk, base, real, inv, out);
    } else {
        float* inv = (float*)d_ws;
        hipLaunchKernelGGL(norm_kernel, dim3((NB + NR) / 4), dim3(256), 0, stream,
                           base, real, inv);
        hipLaunchKernelGGL(simtopk_kernel, dim3(NB / 64), dim3(256), 0, stream,
                           base, real, inv, inv + NB, out);
    }
}